// Round 6
// baseline (4178.223 us; speedup 1.0000x reference)
//
#include <hip/hip_runtime.h>
#include <stdint.h>

#define BATCH 32
#define SEQ   512
#define EDIM  512
#define HID   512            // per-direction hidden
#define NG    2048           // 4*HID gate rows
#define NTAG  16

typedef _Float16 f16;
typedef _Float16 f16x4 __attribute__((ext_vector_type(4)));
typedef _Float16 f16x8 __attribute__((ext_vector_type(8)));
typedef float    f32x4 __attribute__((ext_vector_type(4)));
typedef unsigned u32x4 __attribute__((ext_vector_type(4)));

#define LO_SCALE 2048.0f
#define LO_INV   (1.0f/2048.0f)

// ---------------- prep: fp32 -> f16 hi/lo limb split (lo scaled by 2048) ---
__global__ __launch_bounds__(256) void k_split(const float* __restrict__ src,
                                               f16* __restrict__ hi, f16* __restrict__ lo, int n) {
    int i = blockIdx.x * blockDim.x + threadIdx.x;
    int stride = gridDim.x * blockDim.x;
    for (; i < n; i += stride) {
        float x = src[i];
        f16 h = (f16)x;
        hi[i] = h;
        lo[i] = (f16)((x - (float)h) * LO_SCALE);
    }
}

// ---------------- gather embedding rows + split -----------------------------
__global__ __launch_bounds__(256) void k_gather(const int* __restrict__ sent,
                                                const float* __restrict__ emb,
                                                f16* __restrict__ ehi, f16* __restrict__ elo) {
    int m = blockIdx.x;                  // 0..16383 = b*SEQ+s
    int idx = sent[m];
    const float* src = emb + (size_t)idx * EDIM;
    int k = threadIdx.x * 2;
    float2 v = *(const float2*)(src + k);
    f16 h0 = (f16)v.x, h1 = (f16)v.y;
    ehi[(size_t)m*EDIM + k]     = h0;
    ehi[(size_t)m*EDIM + k + 1] = h1;
    elo[(size_t)m*EDIM + k]     = (f16)((v.x - (float)h0) * LO_SCALE);
    elo[(size_t)m*EDIM + k + 1] = (f16)((v.y - (float)h1) * LO_SCALE);
}

__device__ __forceinline__ void gld16(const void* g, void* l) {
    __builtin_amdgcn_global_load_lds((const __attribute__((address_space(1))) uint32_t*)g,
                                     (__attribute__((address_space(3))) uint32_t*)l, 16, 0, 0);
}
__device__ __forceinline__ f32x4 mfma16(f16x8 a, f16x8 b, f32x4 c) {
    return __builtin_amdgcn_mfma_f32_16x16x32_f16(a, b, c, 0, 0, 0);
}

// ---------------- input projection: X = emb @ Wih^T + bias (f16x2 limbs) ----
__global__ __launch_bounds__(512, 2) void k_gemm(
    const f16* __restrict__ Ahi, const f16* __restrict__ Alo,    // [16384][512]
    const f16* __restrict__ Whi, const f16* __restrict__ Wlo,    // [2][2048][512]
    const float* __restrict__ bias_f, const float* __restrict__ bias_b,
    float* __restrict__ Xout)                                     // [2][16384][2048]
{
    const int n0  = blockIdx.x * 128;
    const int m0  = blockIdx.y * 128;
    const int dir = blockIdx.z;
    const float* bias = dir ? bias_b : bias_f;
    const f16* Bhi = Whi + (size_t)dir * NG * EDIM;
    const f16* Blo = Wlo + (size_t)dir * NG * EDIM;
    float* X = Xout + (size_t)dir * 16384 * NG;

    __shared__ f16 sAh[128*64], sAl[128*64], sBh[128*64], sBl[128*64];  // 64 KiB

    const int tid  = threadIdx.x;
    const int lane = tid & 63;
    const int wave = tid >> 6;        // 0..7
    const int wr   = wave >> 2;       // 0..1  (64 rows)
    const int wc   = wave & 3;        // 0..3  (32 cols)

    f32x4 accH[4][2] = {};
    f32x4 accM[4][2] = {};

    for (int kt = 0; kt < 8; ++kt) {
        const int kbase = kt * 64;
        for (int sub = 0; sub < 2; ++sub) {
            int byte = sub*8192 + tid*16;
            int row  = byte >> 7;          // 0..127
            int up   = (byte >> 4) & 7;
            int u    = up ^ (row & 7);     // logical 16B unit
            const f16* ga  = Ahi + (size_t)(m0 + row)*EDIM + kbase + u*8;
            const f16* gal = Alo + (size_t)(m0 + row)*EDIM + kbase + u*8;
            const f16* gb  = Bhi + (size_t)(n0 + row)*EDIM + kbase + u*8;
            const f16* gbl = Blo + (size_t)(n0 + row)*EDIM + kbase + u*8;
            gld16(ga,  (char*)sAh + byte);
            gld16(gal, (char*)sAl + byte);
            gld16(gb,  (char*)sBh + byte);
            gld16(gbl, (char*)sBl + byte);
        }
        __syncthreads();
        for (int ks = 0; ks < 2; ++ks) {
            f16x8 fAh[4], fAl[4], fBh[2], fBl[2];
            #pragma unroll
            for (int mi = 0; mi < 4; ++mi) {
                int row = wr*64 + mi*16 + (lane & 15);
                int u   = ks*4 + (lane >> 4);
                int off = row*128 + (u ^ (row & 7))*16;
                fAh[mi] = *(const f16x8*)((const char*)sAh + off);
                fAl[mi] = *(const f16x8*)((const char*)sAl + off);
            }
            #pragma unroll
            for (int ni = 0; ni < 2; ++ni) {
                int row = wc*32 + ni*16 + (lane & 15);
                int u   = ks*4 + (lane >> 4);
                int off = row*128 + (u ^ (row & 7))*16;
                fBh[ni] = *(const f16x8*)((const char*)sBh + off);
                fBl[ni] = *(const f16x8*)((const char*)sBl + off);
            }
            #pragma unroll
            for (int mi = 0; mi < 4; ++mi)
                #pragma unroll
                for (int ni = 0; ni < 2; ++ni)
                    accH[mi][ni] = mfma16(fAh[mi], fBh[ni], accH[mi][ni]);
            #pragma unroll
            for (int mi = 0; mi < 4; ++mi)
                #pragma unroll
                for (int ni = 0; ni < 2; ++ni)
                    accM[mi][ni] = mfma16(fAh[mi], fBl[ni], accM[mi][ni]);
            #pragma unroll
            for (int mi = 0; mi < 4; ++mi)
                #pragma unroll
                for (int ni = 0; ni < 2; ++ni)
                    accM[mi][ni] = mfma16(fAl[mi], fBh[ni], accM[mi][ni]);
        }
        __syncthreads();
    }
    #pragma unroll
    for (int ni = 0; ni < 2; ++ni) {
        int col = n0 + wc*32 + ni*16 + (lane & 15);
        float bv = bias[col];
        #pragma unroll
        for (int mi = 0; mi < 4; ++mi) {
            #pragma unroll
            for (int j = 0; j < 4; ++j) {
                int m = m0 + wr*64 + mi*16 + (lane >> 4)*4 + j;
                X[(size_t)m * NG + col] = accH[mi][ni][j] + accM[mi][ni][j]*LO_INV + bv;
            }
        }
    }
}

// ---------------- persistent bidirectional LSTM recurrence (v6) -------------
// 64 WGs: dir(2) x chunk(32, 16 hidden units => 64 gate rows).
// Wave tiling (mt 2 x kq 4): each wave does a K-quarter for ALL 4 gates.
// A-operands load straight from the packed exchange buffer into registers
// (the poll IS the load; no LDS for h at all). B limbs in registers.
// kq-partials reduced via double-buffered gate-contiguous gbuf; 1 barrier/step.
__global__ __launch_bounds__(512, 2) void k_rec(
    const float* __restrict__ Xall,                               // [2][16384][2048]
    const f16* __restrict__ Whi, const f16* __restrict__ Wlo,     // [2][2048][512]
    unsigned* __restrict__ hx,                                    // [2][2][32][512] packed
    float* __restrict__ h_hist)                                   // [16384][1024]
{
    __shared__ float gbuf[2][4*32*16*4];      // [buf][kq][batch32][unit16][gate4] = 64 KiB

    const int wg    = blockIdx.x;
    const int dir   = wg >> 5;
    const int chunk = wg & 31;
    const int u0    = chunk * 16;
    const int tid   = threadIdx.x;
    const int lane  = tid & 63;
    const int wave  = tid >> 6;
    const int kq    = wave & 3;        // K quarter (128 units)
    const int mt    = wave >> 2;       // batch half
    const int u     = lane & 15;
    const int q4    = lane >> 4;

    const float* X = Xall + (size_t)dir * 16384 * NG;
    unsigned* hxd = hx + (size_t)dir * 2 * BATCH * HID;

    const int pb = tid >> 4;          // batch 0..31 (cell thread)
    const int pu = tid & 15;          // hidden unit within chunk (cell thread)
    const int arow = mt*16 + u;       // A batch row for MFMA

    // step-invariant Whh B-fragments -> registers (4 gates x 4 kt x hi/lo)
    f16x8 bhv[4][4], blv[4][4];
    #pragma unroll
    for (int g = 0; g < 4; ++g) {
        const size_t rowb = (size_t)(dir*NG + g*512 + u0 + u) * EDIM + kq*128 + q4*8;
        #pragma unroll
        for (int kt = 0; kt < 4; ++kt) {
            bhv[g][kt] = *(const f16x8*)(Whi + rowb + kt*32);
            blv[g][kt] = *(const f16x8*)(Wlo + rowb + kt*32);
        }
    }

    float c = 0.0f;                   // cell state for (pb,pu)

    for (int t = 0; t < SEQ; ++t) {
        const int s = dir ? (SEQ - 1 - t) : t;

        // X prefetch for the cell phase (latency hides under poll+MFMA)
        float xv[4];
        {
            const float* xb = X + ((size_t)pb*SEQ + s)*NG + u0 + pu;
            #pragma unroll
            for (int g = 0; g < 4; ++g) xv[g] = xb[g*512];
        }

        // ---- poll+load A fragment straight to registers (packed u32) ----
        unsigned pk[32];
        if (t > 0) {
            const unsigned tag32 = (((unsigned)(t - 1) >> 1) & 3u) << 16;
            const unsigned* hsrc = hxd + (size_t)(t & 1)*BATCH*HID
                                 + arow*HID + kq*128 + q4*8;
            for (;;) {
                unsigned bad = 0;
                #pragma unroll
                for (int kt = 0; kt < 4; ++kt) {
                    #pragma unroll
                    for (int p = 0; p < 4; ++p) {
                        unsigned long long v = __hip_atomic_load(
                            (const unsigned long long*)(hsrc + kt*32 + p*2),
                            __ATOMIC_RELAXED, __HIP_MEMORY_SCOPE_AGENT);
                        unsigned w0 = (unsigned)v, w1 = (unsigned)(v >> 32);
                        pk[kt*8 + p*2]     = w0;
                        pk[kt*8 + p*2 + 1] = w1;
                        bad |= (w0 ^ tag32) | (w1 ^ tag32);
                    }
                }
                if (__all((bad & 0x30000u) == 0u)) break;
                __builtin_amdgcn_s_sleep(2);
            }
        }

        // ---- MFMA: partial gates for this wave's (mt, kq) ----
        f32x4 aH[4] = {}, aM1[4] = {}, aM2[4] = {};
        if (t > 0) {
            #pragma unroll
            for (int kt = 0; kt < 4; ++kt) {
                u32x4 hw, lw;
                #pragma unroll
                for (int j = 0; j < 4; ++j) {
                    unsigned w0 = pk[kt*8 + 2*j], w1 = pk[kt*8 + 2*j + 1];
                    hw[j] = (w0 & 0xffffu) | (w1 << 16);
                    lw[j] = (w0 >> 16) | (w1 & 0xffff0000u);
                }
                f16x8 ah = __builtin_bit_cast(f16x8, hw);
                f16x8 al = __builtin_bit_cast(f16x8, lw);
                #pragma unroll
                for (int g = 0; g < 4; ++g) {
                    aH[g]  = mfma16(ah, bhv[g][kt], aH[g]);
                    aM1[g] = mfma16(ah, blv[g][kt], aM1[g]);
                    aM2[g] = mfma16(al, bhv[g][kt], aM2[g]);
                }
            }
        }

        // ---- write kq-partials, gate-contiguous ----
        float* gb = gbuf[t & 1];
        #pragma unroll
        for (int j = 0; j < 4; ++j) {
            int row = mt*16 + q4*4 + j;
            f32x4 v;
            #pragma unroll
            for (int g = 0; g < 4; ++g)
                v[g] = aH[g][j] + (aM1[g][j] + aM2[g][j]) * LO_INV;
            *(f32x4*)(gb + ((kq*32 + row)*16 + u)*4) = v;
        }
        __syncthreads();                       // partials ready

        // ---- pointwise LSTM cell + packed tagged store ----
        {
            const float* gc = gbuf[t & 1];
            f32x4 sv = *(const f32x4*)(gc + ((0*32 + pb)*16 + pu)*4);
            #pragma unroll
            for (int k2 = 1; k2 < 4; ++k2)
                sv += *(const f32x4*)(gc + ((k2*32 + pb)*16 + pu)*4);
            float gi = sv[0] + xv[0];
            float gf = sv[1] + xv[1];
            float gg = sv[2] + xv[2];
            float go = sv[3] + xv[3];
            float si = 1.0f / (1.0f + __expf(-gi));
            float sf = 1.0f / (1.0f + __expf(-gf));
            float tg = 1.0f - 2.0f / (__expf(2.0f*gg) + 1.0f);
            float so = 1.0f / (1.0f + __expf(-go));
            c = sf * c + si * tg;
            float hval = so * (1.0f - 2.0f / (__expf(2.0f*c) + 1.0f));
            f16 hh = (f16)hval;
            f16 hl = (f16)((hval - (float)hh) * LO_SCALE);
            unsigned packed = (unsigned)__builtin_bit_cast(unsigned short, hh)
                            | ((unsigned)__builtin_bit_cast(unsigned short, hl) << 16);
            packed = (packed & ~0x30000u) | ((((unsigned)t >> 1) & 3u) << 16);
            unsigned* hdst = hxd + (size_t)((t + 1) & 1)*BATCH*HID + pb*HID + u0 + pu;
            __hip_atomic_store(hdst, packed, __ATOMIC_RELAXED, __HIP_MEMORY_SCOPE_AGENT);
            // h_hist off the critical path (plain store, drains under next poll)
            h_hist[((size_t)pb*SEQ + s)*1024 + dir*HID + u0 + pu] = hval;
        }
    }
}

// ---------------- output projection: feats = H @ W_out^T + b_out ------------
__global__ __launch_bounds__(256) void k_feats(
    const float* __restrict__ H,      // [16384][1024]
    const float* __restrict__ Wout,   // [16][1024]
    const float* __restrict__ bout,   // [16]
    float* __restrict__ feats)        // [16384][16]
{
    __shared__ float Wt[1024][16];    // 64 KiB, transposed
    int tid = threadIdx.x;
    for (int i = tid; i < 16384; i += 256)
        Wt[i >> 4][i & 15] = Wout[(i & 15)*1024 + (i >> 4)];
    __syncthreads();
    int wave = tid >> 6, lane = tid & 63;
    int row = blockIdx.x * 4 + wave;
    const float* hrow = H + (size_t)row * 1024;
    float acc[16];
    #pragma unroll
    for (int t = 0; t < 16; ++t) acc[t] = 0.f;
    #pragma unroll
    for (int cc = 0; cc < 4; ++cc) {
        float4 hv = *(const float4*)(hrow + cc*256 + lane*4);
        #pragma unroll
        for (int j = 0; j < 4; ++j) {
            int k = cc*256 + lane*4 + j;
            float h = (&hv.x)[j];
            #pragma unroll
            for (int tg = 0; tg < 16; ++tg) acc[tg] += h * Wt[k][tg];
        }
    }
    #pragma unroll
    for (int off = 32; off >= 1; off >>= 1) {
        #pragma unroll
        for (int tg = 0; tg < 16; ++tg) acc[tg] += __shfl_xor(acc[tg], off);
    }
    if (lane == 0) {
        #pragma unroll
        for (int tg = 0; tg < 16; ++tg)
            feats[(size_t)row*16 + tg] = acc[tg] + bout[tg];
    }
}

// ---------------- Viterbi + backtrace (one wave per batch) ------------------
__global__ __launch_bounds__(64) void k_viterbi(
    const float* __restrict__ feats,   // [32][512][16]
    const float* __restrict__ trans,   // [16][16] trans[prev][cur]
    const float* __restrict__ startt, const float* __restrict__ stopt,
    int* __restrict__ out)             // [32][512]
{
    __shared__ unsigned char bp[511*16];
    int b = blockIdx.x;
    int lane = threadIdx.x;
    int cur = lane & 15;
    int q   = lane >> 4;
    float tr[4];
    #pragma unroll
    for (int i = 0; i < 4; ++i) tr[i] = trans[(q*4 + i)*16 + cur];
    const float* fb = feats + (size_t)b * SEQ * NTAG;
    float v = fb[cur] + startt[cur];
    for (int s = 1; s < SEQ; ++s) {
        float best = -1e30f; int bi = 0;
        #pragma unroll
        for (int i = 0; i < 4; ++i) {
            float pv = __shfl(v, q*4 + i);
            float sc = pv + tr[i];
            if (sc > best) { best = sc; bi = q*4 + i; }   // first-max within quarter
        }
        #pragma unroll
        for (int off = 16; off <= 32; off <<= 1) {
            float ob = __shfl_xor(best, off);
            int   oi = __shfl_xor(bi, off);
            if (ob > best || (ob == best && oi < bi)) { best = ob; bi = oi; }
        }
        if (lane < 16) bp[(s - 1)*16 + cur] = (unsigned char)bi;
        v = best + fb[s*16 + cur];
    }
    float sc = v + stopt[cur];
    int bc = cur;
    #pragma unroll
    for (int off = 1; off <= 32; off <<= 1) {
        float os = __shfl_xor(sc, off);
        int   oc = __shfl_xor(bc, off);
        if (os > sc || (os == sc && oc < bc)) { sc = os; bc = oc; }
    }
    __syncthreads();
    if (lane == 0) {
        int curt = bc;
        out[b*SEQ + SEQ - 1] = curt;
        for (int s2 = SEQ - 2; s2 >= 0; --s2) {
            curt = bp[s2*16 + curt];
            out[b*SEQ + s2] = curt;
        }
    }
}

// ---------------- launch ----------------------------------------------------
extern "C" void kernel_launch(void* const* d_in, const int* in_sizes, int n_in,
                              void* d_out, int out_size, void* d_ws, size_t ws_size,
                              hipStream_t stream) {
    (void)in_sizes; (void)n_in; (void)out_size; (void)ws_size;
    const int*   sentence  = (const int*)  d_in[0];
    const float* embedding = (const float*)d_in[1];
    const float* Wih_f = (const float*)d_in[2];
    const float* Whh_f = (const float*)d_in[3];
    const float* b_f   = (const float*)d_in[4];
    const float* Wih_b = (const float*)d_in[5];
    const float* Whh_b = (const float*)d_in[6];
    const float* b_b   = (const float*)d_in[7];
    const float* W_out = (const float*)d_in[8];
    const float* b_out = (const float*)d_in[9];
    const float* trans = (const float*)d_in[10];
    const float* startt= (const float*)d_in[11];
    const float* stopt = (const float*)d_in[12];

    char* ws = (char*)d_ws;
    float* X      = (float*)(ws);                           // 268,435,456 B  [2][16384][2048]
    float* h_hist = (float*)(ws + 268435456ull);            //  67,108,864 B  [16384][1024]
    f16*   ehi    = (f16*)  (ws + 335544320ull);            //  16,777,216 B
    f16*   elo    = (f16*)  (ws + 352321536ull);            //  16,777,216 B
    f16*   wihhi  = (f16*)  (ws + 369098752ull);            //   4,194,304 B
    f16*   wihlo  = (f16*)  (ws + 373293056ull);
    f16*   whhhi  = (f16*)  (ws + 377487360ull);
    f16*   whhlo  = (f16*)  (ws + 381681664ull);
    unsigned* hx  = (unsigned*)(ws + 385875968ull);         //     262,144 B  [2][2][32][512]
    float* feats  = (float*)(ws + 386138112ull);            //   1,048,576 B

    // init exchange buffers: tag field (bits 17:16) = 3, stale vs early tags
    hipMemsetAsync(hx, 0xFF, 262144, stream);

    k_split<<<1024, 256, 0, stream>>>(Wih_f, wihhi,          wihlo,          NG*EDIM);
    k_split<<<1024, 256, 0, stream>>>(Wih_b, wihhi + NG*EDIM, wihlo + NG*EDIM, NG*EDIM);
    k_split<<<1024, 256, 0, stream>>>(Whh_f, whhhi,          whhlo,          NG*EDIM);
    k_split<<<1024, 256, 0, stream>>>(Whh_b, whhhi + NG*EDIM, whhlo + NG*EDIM, NG*EDIM);
    k_gather<<<16384, 256, 0, stream>>>(sentence, embedding, ehi, elo);

    k_gemm<<<dim3(16, 128, 2), 512, 0, stream>>>(ehi, elo, wihhi, wihlo, b_f, b_b, X);

    k_rec<<<64, 512, 0, stream>>>(X, whhhi, whhlo, hx, h_hist);

    k_feats<<<4096, 256, 0, stream>>>(h_hist, W_out, b_out, feats);
    k_viterbi<<<32, 64, 0, stream>>>(feats, trans, startt, stopt, (int*)d_out);
}

// Round 7
// 2886.935 us; speedup vs baseline: 1.4473x; 1.4473x over previous
//
#include <hip/hip_runtime.h>
#include <stdint.h>

#define BATCH 32
#define SEQ   512
#define EDIM  512
#define HID   512            // per-direction hidden
#define NG    2048           // 4*HID gate rows
#define NTAG  16

typedef _Float16 f16;
typedef _Float16 f16x4 __attribute__((ext_vector_type(4)));
typedef _Float16 f16x8 __attribute__((ext_vector_type(8)));
typedef float    f32x4 __attribute__((ext_vector_type(4)));

#define LO_SCALE 2048.0f
#define LO_INV   (1.0f/2048.0f)

// ---------------- prep: fp32 -> f16 hi/lo limb split (lo scaled by 2048) ---
__global__ __launch_bounds__(256) void k_split(const float* __restrict__ src,
                                               f16* __restrict__ hi, f16* __restrict__ lo, int n) {
    int i = blockIdx.x * blockDim.x + threadIdx.x;
    int stride = gridDim.x * blockDim.x;
    for (; i < n; i += stride) {
        float x = src[i];
        f16 h = (f16)x;
        hi[i] = h;
        lo[i] = (f16)((x - (float)h) * LO_SCALE);
    }
}

// ---------------- gather embedding rows + split -----------------------------
__global__ __launch_bounds__(256) void k_gather(const int* __restrict__ sent,
                                                const float* __restrict__ emb,
                                                f16* __restrict__ ehi, f16* __restrict__ elo) {
    int m = blockIdx.x;                  // 0..16383 = b*SEQ+s
    int idx = sent[m];
    const float* src = emb + (size_t)idx * EDIM;
    int k = threadIdx.x * 2;
    float2 v = *(const float2*)(src + k);
    f16 h0 = (f16)v.x, h1 = (f16)v.y;
    ehi[(size_t)m*EDIM + k]     = h0;
    ehi[(size_t)m*EDIM + k + 1] = h1;
    elo[(size_t)m*EDIM + k]     = (f16)((v.x - (float)h0) * LO_SCALE);
    elo[(size_t)m*EDIM + k + 1] = (f16)((v.y - (float)h1) * LO_SCALE);
}

__device__ __forceinline__ void gld16(const void* g, void* l) {
    __builtin_amdgcn_global_load_lds((const __attribute__((address_space(1))) uint32_t*)g,
                                     (__attribute__((address_space(3))) uint32_t*)l, 16, 0, 0);
}
__device__ __forceinline__ f32x4 mfma16(f16x8 a, f16x8 b, f32x4 c) {
    return __builtin_amdgcn_mfma_f32_16x16x32_f16(a, b, c, 0, 0, 0);
}

// ---------------- input projection: X = emb @ Wih^T + bias (f16x2 limbs) ----
__global__ __launch_bounds__(512, 2) void k_gemm(
    const f16* __restrict__ Ahi, const f16* __restrict__ Alo,    // [16384][512]
    const f16* __restrict__ Whi, const f16* __restrict__ Wlo,    // [2][2048][512]
    const float* __restrict__ bias_f, const float* __restrict__ bias_b,
    float* __restrict__ Xout)                                     // [2][16384][2048]
{
    const int n0  = blockIdx.x * 128;
    const int m0  = blockIdx.y * 128;
    const int dir = blockIdx.z;
    const float* bias = dir ? bias_b : bias_f;
    const f16* Bhi = Whi + (size_t)dir * NG * EDIM;
    const f16* Blo = Wlo + (size_t)dir * NG * EDIM;
    float* X = Xout + (size_t)dir * 16384 * NG;

    __shared__ f16 sAh[128*64], sAl[128*64], sBh[128*64], sBl[128*64];  // 64 KiB

    const int tid  = threadIdx.x;
    const int lane = tid & 63;
    const int wave = tid >> 6;        // 0..7
    const int wr   = wave >> 2;       // 0..1  (64 rows)
    const int wc   = wave & 3;        // 0..3  (32 cols)

    f32x4 accH[4][2] = {};
    f32x4 accM[4][2] = {};

    for (int kt = 0; kt < 8; ++kt) {
        const int kbase = kt * 64;
        for (int sub = 0; sub < 2; ++sub) {
            int byte = sub*8192 + tid*16;
            int row  = byte >> 7;          // 0..127
            int up   = (byte >> 4) & 7;
            int u    = up ^ (row & 7);     // logical 16B unit
            const f16* ga  = Ahi + (size_t)(m0 + row)*EDIM + kbase + u*8;
            const f16* gal = Alo + (size_t)(m0 + row)*EDIM + kbase + u*8;
            const f16* gb  = Bhi + (size_t)(n0 + row)*EDIM + kbase + u*8;
            const f16* gbl = Blo + (size_t)(n0 + row)*EDIM + kbase + u*8;
            gld16(ga,  (char*)sAh + byte);
            gld16(gal, (char*)sAl + byte);
            gld16(gb,  (char*)sBh + byte);
            gld16(gbl, (char*)sBl + byte);
        }
        __syncthreads();
        for (int ks = 0; ks < 2; ++ks) {
            f16x8 fAh[4], fAl[4], fBh[2], fBl[2];
            #pragma unroll
            for (int mi = 0; mi < 4; ++mi) {
                int row = wr*64 + mi*16 + (lane & 15);
                int u   = ks*4 + (lane >> 4);
                int off = row*128 + (u ^ (row & 7))*16;
                fAh[mi] = *(const f16x8*)((const char*)sAh + off);
                fAl[mi] = *(const f16x8*)((const char*)sAl + off);
            }
            #pragma unroll
            for (int ni = 0; ni < 2; ++ni) {
                int row = wc*32 + ni*16 + (lane & 15);
                int u   = ks*4 + (lane >> 4);
                int off = row*128 + (u ^ (row & 7))*16;
                fBh[ni] = *(const f16x8*)((const char*)sBh + off);
                fBl[ni] = *(const f16x8*)((const char*)sBl + off);
            }
            #pragma unroll
            for (int mi = 0; mi < 4; ++mi)
                #pragma unroll
                for (int ni = 0; ni < 2; ++ni)
                    accH[mi][ni] = mfma16(fAh[mi], fBh[ni], accH[mi][ni]);
            #pragma unroll
            for (int mi = 0; mi < 4; ++mi)
                #pragma unroll
                for (int ni = 0; ni < 2; ++ni)
                    accM[mi][ni] = mfma16(fAh[mi], fBl[ni], accM[mi][ni]);
            #pragma unroll
            for (int mi = 0; mi < 4; ++mi)
                #pragma unroll
                for (int ni = 0; ni < 2; ++ni)
                    accM[mi][ni] = mfma16(fAl[mi], fBh[ni], accM[mi][ni]);
        }
        __syncthreads();
    }
    #pragma unroll
    for (int ni = 0; ni < 2; ++ni) {
        int col = n0 + wc*32 + ni*16 + (lane & 15);
        float bv = bias[col];
        #pragma unroll
        for (int mi = 0; mi < 4; ++mi) {
            #pragma unroll
            for (int j = 0; j < 4; ++j) {
                int m = m0 + wr*64 + mi*16 + (lane >> 4)*4 + j;
                X[(size_t)m * NG + col] = accH[mi][ni][j] + accM[mi][ni][j]*LO_INV + bv;
            }
        }
    }
}

// ---------------- persistent bidirectional LSTM recurrence (v7) -------------
// 64 WGs = chunk(32) x batch-half(2); each WG runs BOTH directions per step:
//   fill_f -> mfma_f -> cell_f -> fill_b -> mfma_b -> cell_b
// so each direction's L3 visibility latency hides under the other's compute.
// Waves (g 4 x kh 2): one gate-block, one K-half each; B limbs in registers.
// Exchange: packed u32 (f16 hi | f16 lo<<16), 2-bit step tag in bits 17:16;
// per-packet pend-mask poll (r5's proven scheme).
__global__ __launch_bounds__(512, 1) void k_rec(
    const float* __restrict__ Xall,                               // [2][16384][2048]
    const f16* __restrict__ Whi, const f16* __restrict__ Wlo,     // [2][2048][512]
    unsigned* __restrict__ hx,                                    // [2][2][32][512] packed
    float* __restrict__ h_hist)                                   // [16384][1024]
{
    extern __shared__ char smem[];
    char*  pFh = smem;                 // fwd hi plane [16 rows][512 u] swizzled, 16 KiB
    char*  pFl = smem + 16384;         // fwd lo
    char*  pBh = smem + 32768;         // bwd hi
    char*  pBl = smem + 49152;         // bwd lo
    float* gbuf = (float*)(smem + 65536);   // [2 kh][4 g][16 row][17] = 8704 B

    const int wg    = blockIdx.x;
    const int chunk = wg & 31;
    const int mt    = wg >> 5;         // batch half
    const int u0    = chunk * 16;
    const int mrow0 = mt * 16;
    const int tid   = threadIdx.x;
    const int lane  = tid & 63;
    const int wave  = tid >> 6;
    const int g     = wave & 3;        // gate type
    const int kh    = wave >> 2;       // K half
    const int u     = lane & 15;
    const int q4    = lane >> 4;
    const int r7    = u & 7;

    const float* Xf = Xall;
    const float* Xb = Xall + (size_t)16384 * NG;
    const int pbl = (tid >> 4) & 15;   // cell: local batch row (tid<256)
    const int pu  = tid & 15;          // cell: unit within chunk

    // step-invariant Whh B-fragments -> registers: 2 dirs x 8 kt x hi/lo
    f16x8 bhF[8], blF[8], bhB[8], blB[8];
    {
        const size_t rF = (size_t)(0*NG + g*512 + u0 + u) * EDIM + kh*256 + q4*8;
        const size_t rB = (size_t)(1*NG + g*512 + u0 + u) * EDIM + kh*256 + q4*8;
        #pragma unroll
        for (int kt = 0; kt < 8; ++kt) {
            bhF[kt] = *(const f16x8*)(Whi + rF + kt*32);
            blF[kt] = *(const f16x8*)(Wlo + rF + kt*32);
            bhB[kt] = *(const f16x8*)(Whi + rB + kt*32);
            blB[kt] = *(const f16x8*)(Wlo + rB + kt*32);
        }
    }

    float cF = 0.0f, cB = 0.0f;        // cell states for (mrow0+pbl, u0+pu)

    for (int t = 0; t < SEQ; ++t) {
        const int sF = t, sB = SEQ - 1 - t;

        // X prefetch both dirs (latency hides under fills/MFMA)
        float xvF[4], xvB[4];
        if (tid < 256) {
            const float* xbF = Xf + ((size_t)(mrow0 + pbl)*SEQ + sF)*NG + u0 + pu;
            const float* xbB = Xb + ((size_t)(mrow0 + pbl)*SEQ + sB)*NG + u0 + pu;
            #pragma unroll
            for (int gg = 0; gg < 4; ++gg) { xvF[gg] = xbF[gg*512]; xvB[gg] = xbB[gg*512]; }
        }

        // ---- FWD fill (or zero both dirs' planes at t=0) ----
        if (t == 0) {
            #pragma unroll
            for (int i = 0; i < 4; ++i) {
                int q = i*512 + tid, row = q >> 7, kq = (q & 127)*4;
                int off = row*1024 + (((kq >> 3) ^ (row & 7)))*16 + (kq & 4)*2;
                *(uint2*)(pFh + off) = (uint2){0u, 0u};
                *(uint2*)(pFl + off) = (uint2){0u, 0u};
                *(uint2*)(pBh + off) = (uint2){0u, 0u};
                *(uint2*)(pBl + off) = (uint2){0u, 0u};
            }
        } else {
            const unsigned tag32 = (((unsigned)(t - 1) >> 1) & 3u) << 16;
            const unsigned* hsrc = hx + ((size_t)(0*2 + (t & 1))*BATCH + mrow0)*HID;
            unsigned pend = 0xFu;
            while (pend) {
                unsigned long long va[4], vb[4];
                #pragma unroll
                for (int i = 0; i < 4; ++i) if (pend & (1u << i)) {
                    int q = i*512 + tid;
                    const unsigned long long* p =
                        (const unsigned long long*)(hsrc + (q >> 7)*HID + (q & 127)*4);
                    va[i] = __hip_atomic_load(p,     __ATOMIC_RELAXED, __HIP_MEMORY_SCOPE_AGENT);
                    vb[i] = __hip_atomic_load(p + 1, __ATOMIC_RELAXED, __HIP_MEMORY_SCOPE_AGENT);
                }
                #pragma unroll
                for (int i = 0; i < 4; ++i) {
                    if (!(pend & (1u << i))) continue;
                    unsigned w0 = (unsigned)va[i], w1 = (unsigned)(va[i] >> 32);
                    unsigned w2 = (unsigned)vb[i], w3 = (unsigned)(vb[i] >> 32);
                    if ((((w0 ^ tag32) | (w1 ^ tag32) | (w2 ^ tag32) | (w3 ^ tag32)) & 0x30000u) != 0u)
                        continue;
                    unsigned hi01 = (w0 & 0xffffu) | (w1 << 16);
                    unsigned hi23 = (w2 & 0xffffu) | (w3 << 16);
                    unsigned lo01 = (w0 >> 16) | (w1 & 0xffff0000u);
                    unsigned lo23 = (w2 >> 16) | (w3 & 0xffff0000u);
                    int q = i*512 + tid, row = q >> 7, kq = (q & 127)*4;
                    int off = row*1024 + (((kq >> 3) ^ (row & 7)))*16 + (kq & 4)*2;
                    *(uint2*)(pFh + off) = (uint2){hi01, hi23};
                    *(uint2*)(pFl + off) = (uint2){lo01, lo23};
                    pend &= ~(1u << i);
                }
                if (pend) __builtin_amdgcn_s_sleep(1);
            }
        }
        __syncthreads();

        // ---- FWD MFMA ----
        {
            f32x4 aH = {0.f,0.f,0.f,0.f}, aM1 = aH, aM2 = aH;
            #pragma unroll
            for (int kt = 0; kt < 8; ++kt) {
                int ug = (kh*8 + kt)*4 + q4;
                f16x8 ah = *(const f16x8*)(pFh + u*1024 + ((ug ^ r7)*16));
                f16x8 al = *(const f16x8*)(pFl + u*1024 + ((ug ^ r7)*16));
                aH  = mfma16(ah, bhF[kt], aH);
                aM1 = mfma16(ah, blF[kt], aM1);
                aM2 = mfma16(al, bhF[kt], aM2);
            }
            #pragma unroll
            for (int j = 0; j < 4; ++j)
                gbuf[(kh*64 + g*16 + q4*4 + j)*17 + u] = aH[j] + (aM1[j] + aM2[j]) * LO_INV;
        }
        __syncthreads();

        // ---- FWD cell + store ----
        if (tid < 256) {
            float gi = gbuf[(0*64 + 0*16 + pbl)*17 + pu] + gbuf[(1*64 + 0*16 + pbl)*17 + pu] + xvF[0];
            float gf = gbuf[(0*64 + 1*16 + pbl)*17 + pu] + gbuf[(1*64 + 1*16 + pbl)*17 + pu] + xvF[1];
            float gg = gbuf[(0*64 + 2*16 + pbl)*17 + pu] + gbuf[(1*64 + 2*16 + pbl)*17 + pu] + xvF[2];
            float go = gbuf[(0*64 + 3*16 + pbl)*17 + pu] + gbuf[(1*64 + 3*16 + pbl)*17 + pu] + xvF[3];
            float si = 1.0f / (1.0f + __expf(-gi));
            float sf = 1.0f / (1.0f + __expf(-gf));
            float tg = 1.0f - 2.0f / (__expf(2.0f*gg) + 1.0f);
            float so = 1.0f / (1.0f + __expf(-go));
            cF = sf * cF + si * tg;
            float hval = so * (1.0f - 2.0f / (__expf(2.0f*cF) + 1.0f));
            f16 hh = (f16)hval;
            f16 hl = (f16)((hval - (float)hh) * LO_SCALE);
            unsigned packed = (unsigned)__builtin_bit_cast(unsigned short, hh)
                            | ((unsigned)__builtin_bit_cast(unsigned short, hl) << 16);
            packed = (packed & ~0x30000u) | ((((unsigned)t >> 1) & 3u) << 16);
            unsigned* hdst = hx + ((size_t)(0*2 + ((t + 1) & 1))*BATCH + mrow0 + pbl)*HID + u0 + pu;
            __hip_atomic_store(hdst, packed, __ATOMIC_RELAXED, __HIP_MEMORY_SCOPE_AGENT);
            h_hist[((size_t)(mrow0 + pbl)*SEQ + sF)*1024 + 0*HID + u0 + pu] = hval;
        }

        // ---- BWD fill ----
        if (t > 0) {
            const unsigned tag32 = (((unsigned)(t - 1) >> 1) & 3u) << 16;
            const unsigned* hsrc = hx + ((size_t)(1*2 + (t & 1))*BATCH + mrow0)*HID;
            unsigned pend = 0xFu;
            while (pend) {
                unsigned long long va[4], vb[4];
                #pragma unroll
                for (int i = 0; i < 4; ++i) if (pend & (1u << i)) {
                    int q = i*512 + tid;
                    const unsigned long long* p =
                        (const unsigned long long*)(hsrc + (q >> 7)*HID + (q & 127)*4);
                    va[i] = __hip_atomic_load(p,     __ATOMIC_RELAXED, __HIP_MEMORY_SCOPE_AGENT);
                    vb[i] = __hip_atomic_load(p + 1, __ATOMIC_RELAXED, __HIP_MEMORY_SCOPE_AGENT);
                }
                #pragma unroll
                for (int i = 0; i < 4; ++i) {
                    if (!(pend & (1u << i))) continue;
                    unsigned w0 = (unsigned)va[i], w1 = (unsigned)(va[i] >> 32);
                    unsigned w2 = (unsigned)vb[i], w3 = (unsigned)(vb[i] >> 32);
                    if ((((w0 ^ tag32) | (w1 ^ tag32) | (w2 ^ tag32) | (w3 ^ tag32)) & 0x30000u) != 0u)
                        continue;
                    unsigned hi01 = (w0 & 0xffffu) | (w1 << 16);
                    unsigned hi23 = (w2 & 0xffffu) | (w3 << 16);
                    unsigned lo01 = (w0 >> 16) | (w1 & 0xffff0000u);
                    unsigned lo23 = (w2 >> 16) | (w3 & 0xffff0000u);
                    int q = i*512 + tid, row = q >> 7, kq = (q & 127)*4;
                    int off = row*1024 + (((kq >> 3) ^ (row & 7)))*16 + (kq & 4)*2;
                    *(uint2*)(pBh + off) = (uint2){hi01, hi23};
                    *(uint2*)(pBl + off) = (uint2){lo01, lo23};
                    pend &= ~(1u << i);
                }
                if (pend) __builtin_amdgcn_s_sleep(1);
            }
        }
        __syncthreads();

        // ---- BWD MFMA ----
        {
            f32x4 aH = {0.f,0.f,0.f,0.f}, aM1 = aH, aM2 = aH;
            #pragma unroll
            for (int kt = 0; kt < 8; ++kt) {
                int ug = (kh*8 + kt)*4 + q4;
                f16x8 ah = *(const f16x8*)(pBh + u*1024 + ((ug ^ r7)*16));
                f16x8 al = *(const f16x8*)(pBl + u*1024 + ((ug ^ r7)*16));
                aH  = mfma16(ah, bhB[kt], aH);
                aM1 = mfma16(ah, blB[kt], aM1);
                aM2 = mfma16(al, bhB[kt], aM2);
            }
            #pragma unroll
            for (int j = 0; j < 4; ++j)
                gbuf[(kh*64 + g*16 + q4*4 + j)*17 + u] = aH[j] + (aM1[j] + aM2[j]) * LO_INV;
        }
        __syncthreads();

        // ---- BWD cell + store ----
        if (tid < 256) {
            float gi = gbuf[(0*64 + 0*16 + pbl)*17 + pu] + gbuf[(1*64 + 0*16 + pbl)*17 + pu] + xvB[0];
            float gf = gbuf[(0*64 + 1*16 + pbl)*17 + pu] + gbuf[(1*64 + 1*16 + pbl)*17 + pu] + xvB[1];
            float gg = gbuf[(0*64 + 2*16 + pbl)*17 + pu] + gbuf[(1*64 + 2*16 + pbl)*17 + pu] + xvB[2];
            float go = gbuf[(0*64 + 3*16 + pbl)*17 + pu] + gbuf[(1*64 + 3*16 + pbl)*17 + pu] + xvB[3];
            float si = 1.0f / (1.0f + __expf(-gi));
            float sf = 1.0f / (1.0f + __expf(-gf));
            float tg = 1.0f - 2.0f / (__expf(2.0f*gg) + 1.0f);
            float so = 1.0f / (1.0f + __expf(-go));
            cB = sf * cB + si * tg;
            float hval = so * (1.0f - 2.0f / (__expf(2.0f*cB) + 1.0f));
            f16 hh = (f16)hval;
            f16 hl = (f16)((hval - (float)hh) * LO_SCALE);
            unsigned packed = (unsigned)__builtin_bit_cast(unsigned short, hh)
                            | ((unsigned)__builtin_bit_cast(unsigned short, hl) << 16);
            packed = (packed & ~0x30000u) | ((((unsigned)t >> 1) & 3u) << 16);
            unsigned* hdst = hx + ((size_t)(1*2 + ((t + 1) & 1))*BATCH + mrow0 + pbl)*HID + u0 + pu;
            __hip_atomic_store(hdst, packed, __ATOMIC_RELAXED, __HIP_MEMORY_SCOPE_AGENT);
            h_hist[((size_t)(mrow0 + pbl)*SEQ + sB)*1024 + 1*HID + u0 + pu] = hval;
        }
    }
}

// ---------------- output projection: feats = H @ W_out^T + b_out ------------
__global__ __launch_bounds__(256) void k_feats(
    const float* __restrict__ H,      // [16384][1024]
    const float* __restrict__ Wout,   // [16][1024]
    const float* __restrict__ bout,   // [16]
    float* __restrict__ feats)        // [16384][16]
{
    __shared__ float Wt[1024][16];    // 64 KiB, transposed
    int tid = threadIdx.x;
    for (int i = tid; i < 16384; i += 256)
        Wt[i >> 4][i & 15] = Wout[(i & 15)*1024 + (i >> 4)];
    __syncthreads();
    int wave = tid >> 6, lane = tid & 63;
    int row = blockIdx.x * 4 + wave;
    const float* hrow = H + (size_t)row * 1024;
    float acc[16];
    #pragma unroll
    for (int t = 0; t < 16; ++t) acc[t] = 0.f;
    #pragma unroll
    for (int cc = 0; cc < 4; ++cc) {
        float4 hv = *(const float4*)(hrow + cc*256 + lane*4);
        #pragma unroll
        for (int j = 0; j < 4; ++j) {
            int k = cc*256 + lane*4 + j;
            float h = (&hv.x)[j];
            #pragma unroll
            for (int tg = 0; tg < 16; ++tg) acc[tg] += h * Wt[k][tg];
        }
    }
    #pragma unroll
    for (int off = 32; off >= 1; off >>= 1) {
        #pragma unroll
        for (int tg = 0; tg < 16; ++tg) acc[tg] += __shfl_xor(acc[tg], off);
    }
    if (lane == 0) {
        #pragma unroll
        for (int tg = 0; tg < 16; ++tg)
            feats[(size_t)row*16 + tg] = acc[tg] + bout[tg];
    }
}

// ---------------- Viterbi + backtrace (one wave per batch) ------------------
__global__ __launch_bounds__(64) void k_viterbi(
    const float* __restrict__ feats,   // [32][512][16]
    const float* __restrict__ trans,   // [16][16] trans[prev][cur]
    const float* __restrict__ startt, const float* __restrict__ stopt,
    int* __restrict__ out)             // [32][512]
{
    __shared__ unsigned char bp[511*16];
    int b = blockIdx.x;
    int lane = threadIdx.x;
    int cur = lane & 15;
    int q   = lane >> 4;
    float tr[4];
    #pragma unroll
    for (int i = 0; i < 4; ++i) tr[i] = trans[(q*4 + i)*16 + cur];
    const float* fb = feats + (size_t)b * SEQ * NTAG;
    float v = fb[cur] + startt[cur];
    for (int s = 1; s < SEQ; ++s) {
        float best = -1e30f; int bi = 0;
        #pragma unroll
        for (int i = 0; i < 4; ++i) {
            float pv = __shfl(v, q*4 + i);
            float sc = pv + tr[i];
            if (sc > best) { best = sc; bi = q*4 + i; }   // first-max within quarter
        }
        #pragma unroll
        for (int off = 16; off <= 32; off <<= 1) {
            float ob = __shfl_xor(best, off);
            int   oi = __shfl_xor(bi, off);
            if (ob > best || (ob == best && oi < bi)) { best = ob; bi = oi; }
        }
        if (lane < 16) bp[(s - 1)*16 + cur] = (unsigned char)bi;
        v = best + fb[s*16 + cur];
    }
    float sc = v + stopt[cur];
    int bc = cur;
    #pragma unroll
    for (int off = 1; off <= 32; off <<= 1) {
        float os = __shfl_xor(sc, off);
        int   oc = __shfl_xor(bc, off);
        if (os > sc || (os == sc && oc < bc)) { sc = os; bc = oc; }
    }
    __syncthreads();
    if (lane == 0) {
        int curt = bc;
        out[b*SEQ + SEQ - 1] = curt;
        for (int s2 = SEQ - 2; s2 >= 0; --s2) {
            curt = bp[s2*16 + curt];
            out[b*SEQ + s2] = curt;
        }
    }
}

// ---------------- launch ----------------------------------------------------
extern "C" void kernel_launch(void* const* d_in, const int* in_sizes, int n_in,
                              void* d_out, int out_size, void* d_ws, size_t ws_size,
                              hipStream_t stream) {
    (void)in_sizes; (void)n_in; (void)out_size; (void)ws_size;
    const int*   sentence  = (const int*)  d_in[0];
    const float* embedding = (const float*)d_in[1];
    const float* Wih_f = (const float*)d_in[2];
    const float* Whh_f = (const float*)d_in[3];
    const float* b_f   = (const float*)d_in[4];
    const float* Wih_b = (const float*)d_in[5];
    const float* Whh_b = (const float*)d_in[6];
    const float* b_b   = (const float*)d_in[7];
    const float* W_out = (const float*)d_in[8];
    const float* b_out = (const float*)d_in[9];
    const float* trans = (const float*)d_in[10];
    const float* startt= (const float*)d_in[11];
    const float* stopt = (const float*)d_in[12];

    char* ws = (char*)d_ws;
    float* X      = (float*)(ws);                           // 268,435,456 B  [2][16384][2048]
    float* h_hist = (float*)(ws + 268435456ull);            //  67,108,864 B  [16384][1024]
    f16*   ehi    = (f16*)  (ws + 335544320ull);            //  16,777,216 B
    f16*   elo    = (f16*)  (ws + 352321536ull);            //  16,777,216 B
    f16*   wihhi  = (f16*)  (ws + 369098752ull);            //   4,194,304 B
    f16*   wihlo  = (f16*)  (ws + 373293056ull);
    f16*   whhhi  = (f16*)  (ws + 377487360ull);
    f16*   whhlo  = (f16*)  (ws + 381681664ull);
    unsigned* hx  = (unsigned*)(ws + 385875968ull);         //     262,144 B  [2][2][32][512]
    float* feats  = (float*)(ws + 386138112ull);            //   1,048,576 B

    // init exchange buffers: tag field (bits 17:16) = 3
    hipMemsetAsync(hx, 0xFF, 262144, stream);

    k_split<<<1024, 256, 0, stream>>>(Wih_f, wihhi,          wihlo,          NG*EDIM);
    k_split<<<1024, 256, 0, stream>>>(Wih_b, wihhi + NG*EDIM, wihlo + NG*EDIM, NG*EDIM);
    k_split<<<1024, 256, 0, stream>>>(Whh_f, whhhi,          whhlo,          NG*EDIM);
    k_split<<<1024, 256, 0, stream>>>(Whh_b, whhhi + NG*EDIM, whhlo + NG*EDIM, NG*EDIM);
    k_gather<<<16384, 256, 0, stream>>>(sentence, embedding, ehi, elo);

    k_gemm<<<dim3(16, 128, 2), 512, 0, stream>>>(ehi, elo, wihhi, wihlo, b_f, b_b, X);

    hipFuncSetAttribute((const void*)k_rec, hipFuncAttributeMaxDynamicSharedMemorySize, 74240);
    k_rec<<<64, 512, 74240, stream>>>(X, whhhi, whhlo, hx, h_hist);

    k_feats<<<4096, 256, 0, stream>>>(h_hist, W_out, b_out, feats);
    k_viterbi<<<32, 64, 0, stream>>>(feats, trans, startt, stopt, (int*)d_out);
}

// Round 8
// 2886.883 us; speedup vs baseline: 1.4473x; 1.0000x over previous
//
#include <hip/hip_runtime.h>
#include <stdint.h>

#define BATCH 32
#define SEQ   512
#define EDIM  512
#define HID   512            // per-direction hidden
#define NG    2048           // 4*HID gate rows
#define NTAG  16

typedef _Float16 f16;
typedef _Float16 f16x4 __attribute__((ext_vector_type(4)));
typedef _Float16 f16x8 __attribute__((ext_vector_type(8)));
typedef float    f32x4 __attribute__((ext_vector_type(4)));

#define LO_SCALE 2048.0f
#define LO_INV   (1.0f/2048.0f)

// ---------------- prep: fp32 -> f16 hi/lo limb split (lo scaled by 2048) ---
__global__ __launch_bounds__(256) void k_split(const float* __restrict__ src,
                                               f16* __restrict__ hi, f16* __restrict__ lo, int n) {
    int i = blockIdx.x * blockDim.x + threadIdx.x;
    int stride = gridDim.x * blockDim.x;
    for (; i < n; i += stride) {
        float x = src[i];
        f16 h = (f16)x;
        hi[i] = h;
        lo[i] = (f16)((x - (float)h) * LO_SCALE);
    }
}

// ---------------- gather embedding rows + split -----------------------------
__global__ __launch_bounds__(256) void k_gather(const int* __restrict__ sent,
                                                const float* __restrict__ emb,
                                                f16* __restrict__ ehi, f16* __restrict__ elo) {
    int m = blockIdx.x;                  // 0..16383 = b*SEQ+s
    int idx = sent[m];
    const float* src = emb + (size_t)idx * EDIM;
    int k = threadIdx.x * 2;
    float2 v = *(const float2*)(src + k);
    f16 h0 = (f16)v.x, h1 = (f16)v.y;
    ehi[(size_t)m*EDIM + k]     = h0;
    ehi[(size_t)m*EDIM + k + 1] = h1;
    elo[(size_t)m*EDIM + k]     = (f16)((v.x - (float)h0) * LO_SCALE);
    elo[(size_t)m*EDIM + k + 1] = (f16)((v.y - (float)h1) * LO_SCALE);
}

__device__ __forceinline__ void gld16(const void* g, void* l) {
    __builtin_amdgcn_global_load_lds((const __attribute__((address_space(1))) uint32_t*)g,
                                     (__attribute__((address_space(3))) uint32_t*)l, 16, 0, 0);
}
__device__ __forceinline__ f32x4 mfma16(f16x8 a, f16x8 b, f32x4 c) {
    return __builtin_amdgcn_mfma_f32_16x16x32_f16(a, b, c, 0, 0, 0);
}

// ---------------- input projection: X = emb @ Wih^T + bias (f16x2 limbs) ----
// Output layout: X[dir][chunk 32][batch 32][seq 512][gate 4][unit 16] (f32)
// so k_rec's per-(chunk,batch) step read is a contiguous 256B stream.
__global__ __launch_bounds__(512, 2) void k_gemm(
    const f16* __restrict__ Ahi, const f16* __restrict__ Alo,    // [16384][512]
    const f16* __restrict__ Whi, const f16* __restrict__ Wlo,    // [2][2048][512]
    const float* __restrict__ bias_f, const float* __restrict__ bias_b,
    float* __restrict__ Xout)
{
    const int n0  = blockIdx.x * 128;
    const int m0  = blockIdx.y * 128;
    const int dir = blockIdx.z;
    const float* bias = dir ? bias_b : bias_f;
    const f16* Bhi = Whi + (size_t)dir * NG * EDIM;
    const f16* Blo = Wlo + (size_t)dir * NG * EDIM;
    float* X = Xout + (size_t)dir * 16384 * NG;

    __shared__ f16 sAh[128*64], sAl[128*64], sBh[128*64], sBl[128*64];  // 64 KiB

    const int tid  = threadIdx.x;
    const int lane = tid & 63;
    const int wave = tid >> 6;        // 0..7
    const int wr   = wave >> 2;       // 0..1  (64 rows)
    const int wc   = wave & 3;        // 0..3  (32 cols)

    f32x4 accH[4][2] = {};
    f32x4 accM[4][2] = {};

    for (int kt = 0; kt < 8; ++kt) {
        const int kbase = kt * 64;
        for (int sub = 0; sub < 2; ++sub) {
            int byte = sub*8192 + tid*16;
            int row  = byte >> 7;          // 0..127
            int up   = (byte >> 4) & 7;
            int u    = up ^ (row & 7);     // logical 16B unit
            const f16* ga  = Ahi + (size_t)(m0 + row)*EDIM + kbase + u*8;
            const f16* gal = Alo + (size_t)(m0 + row)*EDIM + kbase + u*8;
            const f16* gb  = Bhi + (size_t)(n0 + row)*EDIM + kbase + u*8;
            const f16* gbl = Blo + (size_t)(n0 + row)*EDIM + kbase + u*8;
            gld16(ga,  (char*)sAh + byte);
            gld16(gal, (char*)sAl + byte);
            gld16(gb,  (char*)sBh + byte);
            gld16(gbl, (char*)sBl + byte);
        }
        __syncthreads();
        for (int ks = 0; ks < 2; ++ks) {
            f16x8 fAh[4], fAl[4], fBh[2], fBl[2];
            #pragma unroll
            for (int mi = 0; mi < 4; ++mi) {
                int row = wr*64 + mi*16 + (lane & 15);
                int u   = ks*4 + (lane >> 4);
                int off = row*128 + (u ^ (row & 7))*16;
                fAh[mi] = *(const f16x8*)((const char*)sAh + off);
                fAl[mi] = *(const f16x8*)((const char*)sAl + off);
            }
            #pragma unroll
            for (int ni = 0; ni < 2; ++ni) {
                int row = wc*32 + ni*16 + (lane & 15);
                int u   = ks*4 + (lane >> 4);
                int off = row*128 + (u ^ (row & 7))*16;
                fBh[ni] = *(const f16x8*)((const char*)sBh + off);
                fBl[ni] = *(const f16x8*)((const char*)sBl + off);
            }
            #pragma unroll
            for (int mi = 0; mi < 4; ++mi)
                #pragma unroll
                for (int ni = 0; ni < 2; ++ni)
                    accH[mi][ni] = mfma16(fAh[mi], fBh[ni], accH[mi][ni]);
            #pragma unroll
            for (int mi = 0; mi < 4; ++mi)
                #pragma unroll
                for (int ni = 0; ni < 2; ++ni)
                    accM[mi][ni] = mfma16(fAh[mi], fBl[ni], accM[mi][ni]);
            #pragma unroll
            for (int mi = 0; mi < 4; ++mi)
                #pragma unroll
                for (int ni = 0; ni < 2; ++ni)
                    accM[mi][ni] = mfma16(fAl[mi], fBh[ni], accM[mi][ni]);
        }
        __syncthreads();
    }
    // epilogue: write relayout [chunk][b][s][gate][unit]
    #pragma unroll
    for (int ni = 0; ni < 2; ++ni) {
        int col = n0 + wc*32 + ni*16 + (lane & 15);
        float bv = bias[col];
        int gate  = col >> 9;
        int chunk = (col >> 4) & 31;
        int u     = col & 15;
        #pragma unroll
        for (int mi = 0; mi < 4; ++mi) {
            #pragma unroll
            for (int j = 0; j < 4; ++j) {
                int m = m0 + wr*64 + mi*16 + (lane >> 4)*4 + j;
                int b = m >> 9, s = m & 511;
                X[(((size_t)chunk*32 + b)*512 + s)*64 + gate*16 + u] =
                    accH[mi][ni][j] + accM[mi][ni][j]*LO_INV + bv;
            }
        }
    }
}

// ---------------- persistent bidirectional LSTM recurrence (v8 = v5 + X relayout
// + busy poll + NT h_hist) ----------------------------------------------------
// 64 WGs: dir(2) x chunk(32, 16 hidden units => 64 gate rows).
// Wave tiling (mt, g2, kh); LDS h limb planes; packed u32 exchange with 2-bit
// step tag in bits 17:16; per-packet pend-mask poll (no sleep).
__global__ __launch_bounds__(512, 1) void k_rec(
    const float* __restrict__ Xall,                               // [2][32][32][512][64]
    const f16* __restrict__ Whi, const f16* __restrict__ Wlo,     // [2][2048][512]
    unsigned* __restrict__ hx,                                    // [2][2][32][512] packed
    float* __restrict__ h_hist)                                   // [16384][1024]
{
    extern __shared__ char smem[];
    char*  hhiS = smem;                       // h hi plane [32][64 x 16B] swizzled
    char*  hloS = smem + 32768;               // h lo plane
    float* gbuf = (float*)(smem + 65536);     // [2][4*32*17]

    const int wg    = blockIdx.x;
    const int dir   = wg >> 5;
    const int chunk = wg & 31;
    const int u0    = chunk * 16;
    const int tid   = threadIdx.x;
    const int lane  = tid & 63;
    const int wave  = tid >> 6;
    const int mt    = wave & 1;        // batch half
    const int kh    = (wave >> 1) & 1; // K half
    const int g2    = wave >> 2;       // gate-pair block (gates 2*g2, 2*g2+1)
    const int u     = lane & 15;
    const int q4    = lane >> 4;

    const float* X = Xall + (size_t)dir * 16384 * NG;   // dir slice (same elem count)
    unsigned* hxd = hx + (size_t)dir * 2 * BATCH * HID;

    const int pb = tid >> 4;          // batch 0..31 (cell thread)
    const int pu = tid & 15;          // hidden unit within chunk (cell thread)
    const int arow  = mt*16 + u;      // A batch row
    const char* hrowH = hhiS + arow*1024;
    const char* hrowL = hloS + arow*1024;
    const int arow7 = arow & 7;

    // step-invariant Whh B-fragments -> registers (2 gates x 8 kt x hi/lo)
    f16x8 bhv[2][8], blv[2][8];
    #pragma unroll
    for (int gt = 0; gt < 2; ++gt) {
        const size_t row = (size_t)(dir*NG + (g2*2 + gt)*512 + u0 + u) * EDIM;
        const f16* ph = Whi + row + q4*8;
        const f16* pl = Wlo + row + q4*8;
        #pragma unroll
        for (int kt = 0; kt < 8; ++kt) {
            bhv[gt][kt] = *(const f16x8*)(ph + (kh*8 + kt)*32);
            blv[gt][kt] = *(const f16x8*)(pl + (kh*8 + kt)*32);
        }
    }

    float c = 0.0f;                   // cell state for (pb,pu)

    for (int t = 0; t < SEQ; ++t) {
        const int s = dir ? (SEQ - 1 - t) : t;

        // X prefetch for the cell phase (contiguous 64B/row stream now)
        float xv[4];
        {
            const float* xb = X + (((size_t)chunk*32 + pb)*512 + s)*64 + pu;
            #pragma unroll
            for (int g = 0; g < 4; ++g) xv[g] = xb[g*16];
        }

        // fill h planes (poll packed data for this step's tag; busy retry)
        if (t == 0) {
            #pragma unroll
            for (int i = 0; i < 8; ++i) {
                int q = i*512 + tid, batch = q >> 7, kq = (q & 127)*4;
                int off = batch*1024 + ((kq >> 3) ^ (batch & 7))*16 + (kq & 4)*2;
                *(uint2*)(hhiS + off) = (uint2){0u, 0u};
                *(uint2*)(hloS + off) = (uint2){0u, 0u};
            }
        } else {
            const unsigned tag32 = ((unsigned)((t - 1) >> 1) & 3u) << 16;
            const unsigned* hsrc = hxd + (size_t)(t & 1) * BATCH * HID;
            unsigned pend = 0xffu;
            while (pend) {
                unsigned long long va[8], vb[8];
                #pragma unroll
                for (int i = 0; i < 8; ++i) {
                    if (pend & (1u << i)) {
                        int q = i*512 + tid;
                        const unsigned long long* p =
                            (const unsigned long long*)(hsrc + (q >> 7)*HID + (q & 127)*4);
                        va[i] = __hip_atomic_load(p,     __ATOMIC_RELAXED, __HIP_MEMORY_SCOPE_AGENT);
                        vb[i] = __hip_atomic_load(p + 1, __ATOMIC_RELAXED, __HIP_MEMORY_SCOPE_AGENT);
                    }
                }
                #pragma unroll
                for (int i = 0; i < 8; ++i) {
                    if (!(pend & (1u << i))) continue;
                    unsigned w0 = (unsigned)va[i], w1 = (unsigned)(va[i] >> 32);
                    unsigned w2 = (unsigned)vb[i], w3 = (unsigned)(vb[i] >> 32);
                    if ((((w0 ^ tag32) | (w1 ^ tag32) | (w2 ^ tag32) | (w3 ^ tag32)) & 0x30000u) != 0u)
                        continue;   // not all words carry this step's tag yet
                    unsigned hi01 = (w0 & 0xffffu) | (w1 << 16);
                    unsigned hi23 = (w2 & 0xffffu) | (w3 << 16);
                    unsigned lo01 = (w0 >> 16) | (w1 & 0xffff0000u);
                    unsigned lo23 = (w2 >> 16) | (w3 & 0xffff0000u);
                    int q = i*512 + tid, batch = q >> 7, kq = (q & 127)*4;
                    int off = batch*1024 + ((kq >> 3) ^ (batch & 7))*16 + (kq & 4)*2;
                    *(uint2*)(hhiS + off) = (uint2){hi01, hi23};
                    *(uint2*)(hloS + off) = (uint2){lo01, lo23};
                    pend &= ~(1u << i);
                }
            }
        }
        __syncthreads();                       // (1) fill done

        // MFMA: partial gates = h @ Whh^T for this wave's (mt, g2, kh)
        f32x4 accH[2] = {}, accMa[2] = {}, accMb[2] = {};
        #pragma unroll
        for (int kt = 0; kt < 8; ++kt) {
            int ug = (kh*8 + kt)*4 + q4;
            f16x8 ah = *(const f16x8*)(hrowH + (ug ^ arow7)*16);
            f16x8 al = *(const f16x8*)(hrowL + (ug ^ arow7)*16);
            #pragma unroll
            for (int gt = 0; gt < 2; ++gt) {
                accH[gt]  = mfma16(ah, bhv[gt][kt], accH[gt]);
                accMa[gt] = mfma16(ah, blv[gt][kt], accMa[gt]);
                accMb[gt] = mfma16(al, bhv[gt][kt], accMb[gt]);
            }
        }
        #pragma unroll
        for (int gt = 0; gt < 2; ++gt) {
            f32x4 rH = accH[gt];
            f32x4 rM = accMa[gt] + accMb[gt];
            #pragma unroll
            for (int j = 0; j < 4; ++j) {
                int row = (g2*2 + gt)*32 + mt*16 + q4*4 + j;   // gtype*32 + batch
                gbuf[kh*2176 + row*17 + u] = rH[j] + rM[j]*LO_INV;
            }
        }
        __syncthreads();                       // (2) gbuf ready; plane reads done

        // pointwise LSTM cell + packed tagged store
        {
            float gs[4];
            #pragma unroll
            for (int g = 0; g < 4; ++g)
                gs[g] = gbuf[(g*32 + pb)*17 + pu] + gbuf[2176 + (g*32 + pb)*17 + pu] + xv[g];
            float si = 1.0f / (1.0f + __expf(-gs[0]));
            float sf = 1.0f / (1.0f + __expf(-gs[1]));
            float tg = 1.0f - 2.0f / (__expf(2.0f*gs[2]) + 1.0f);
            float so = 1.0f / (1.0f + __expf(-gs[3]));
            c = sf * c + si * tg;
            float hval = so * (1.0f - 2.0f / (__expf(2.0f*c) + 1.0f));
            f16 hh = (f16)hval;
            f16 hl = (f16)((hval - (float)hh) * LO_SCALE);
            unsigned packed = (unsigned)__builtin_bit_cast(unsigned short, hh)
                            | ((unsigned)__builtin_bit_cast(unsigned short, hl) << 16);
            packed = (packed & ~0x30000u) | ((((unsigned)t >> 1) & 3u) << 16);
            unsigned* hdst = hxd + (size_t)((t + 1) & 1)*BATCH*HID + pb*HID + u0 + pu;
            __hip_atomic_store(hdst, packed, __ATOMIC_RELAXED, __HIP_MEMORY_SCOPE_AGENT);
            // h_hist off the critical path; non-temporal (keep L2 clean)
            __builtin_nontemporal_store(hval,
                h_hist + ((size_t)pb*SEQ + s)*1024 + dir*HID + u0 + pu);
        }
    }
}

// ---------------- output projection: feats = H @ W_out^T + b_out ------------
__global__ __launch_bounds__(256) void k_feats(
    const float* __restrict__ H,      // [16384][1024]
    const float* __restrict__ Wout,   // [16][1024]
    const float* __restrict__ bout,   // [16]
    float* __restrict__ feats)        // [16384][16]
{
    __shared__ float Wt[1024][16];    // 64 KiB, transposed
    int tid = threadIdx.x;
    for (int i = tid; i < 16384; i += 256)
        Wt[i >> 4][i & 15] = Wout[(i & 15)*1024 + (i >> 4)];
    __syncthreads();
    int wave = tid >> 6, lane = tid & 63;
    int row = blockIdx.x * 4 + wave;
    const float* hrow = H + (size_t)row * 1024;
    float acc[16];
    #pragma unroll
    for (int t = 0; t < 16; ++t) acc[t] = 0.f;
    #pragma unroll
    for (int cc = 0; cc < 4; ++cc) {
        float4 hv = *(const float4*)(hrow + cc*256 + lane*4);
        #pragma unroll
        for (int j = 0; j < 4; ++j) {
            int k = cc*256 + lane*4 + j;
            float h = (&hv.x)[j];
            #pragma unroll
            for (int tg = 0; tg < 16; ++tg) acc[tg] += h * Wt[k][tg];
        }
    }
    #pragma unroll
    for (int off = 32; off >= 1; off >>= 1) {
        #pragma unroll
        for (int tg = 0; tg < 16; ++tg) acc[tg] += __shfl_xor(acc[tg], off);
    }
    if (lane == 0) {
        #pragma unroll
        for (int tg = 0; tg < 16; ++tg)
            feats[(size_t)row*16 + tg] = acc[tg] + bout[tg];
    }
}

// ---------------- Viterbi + backtrace (one wave per batch) ------------------
__global__ __launch_bounds__(64) void k_viterbi(
    const float* __restrict__ feats,   // [32][512][16]
    const float* __restrict__ trans,   // [16][16] trans[prev][cur]
    const float* __restrict__ startt, const float* __restrict__ stopt,
    int* __restrict__ out)             // [32][512]
{
    __shared__ unsigned char bp[511*16];
    int b = blockIdx.x;
    int lane = threadIdx.x;
    int cur = lane & 15;
    int q   = lane >> 4;
    float tr[4];
    #pragma unroll
    for (int i = 0; i < 4; ++i) tr[i] = trans[(q*4 + i)*16 + cur];
    const float* fb = feats + (size_t)b * SEQ * NTAG;
    float v = fb[cur] + startt[cur];
    for (int s = 1; s < SEQ; ++s) {
        float best = -1e30f; int bi = 0;
        #pragma unroll
        for (int i = 0; i < 4; ++i) {
            float pv = __shfl(v, q*4 + i);
            float sc = pv + tr[i];
            if (sc > best) { best = sc; bi = q*4 + i; }   // first-max within quarter
        }
        #pragma unroll
        for (int off = 16; off <= 32; off <<= 1) {
            float ob = __shfl_xor(best, off);
            int   oi = __shfl_xor(bi, off);
            if (ob > best || (ob == best && oi < bi)) { best = ob; bi = oi; }
        }
        if (lane < 16) bp[(s - 1)*16 + cur] = (unsigned char)bi;
        v = best + fb[s*16 + cur];
    }
    float sc = v + stopt[cur];
    int bc = cur;
    #pragma unroll
    for (int off = 1; off <= 32; off <<= 1) {
        float os = __shfl_xor(sc, off);
        int   oc = __shfl_xor(bc, off);
        if (os > sc || (os == sc && oc < bc)) { sc = os; bc = oc; }
    }
    __syncthreads();
    if (lane == 0) {
        int curt = bc;
        out[b*SEQ + SEQ - 1] = curt;
        for (int s2 = SEQ - 2; s2 >= 0; --s2) {
            curt = bp[s2*16 + curt];
            out[b*SEQ + s2] = curt;
        }
    }
}

// ---------------- launch ----------------------------------------------------
extern "C" void kernel_launch(void* const* d_in, const int* in_sizes, int n_in,
                              void* d_out, int out_size, void* d_ws, size_t ws_size,
                              hipStream_t stream) {
    (void)in_sizes; (void)n_in; (void)out_size; (void)ws_size;
    const int*   sentence  = (const int*)  d_in[0];
    const float* embedding = (const float*)d_in[1];
    const float* Wih_f = (const float*)d_in[2];
    const float* Whh_f = (const float*)d_in[3];
    const float* b_f   = (const float*)d_in[4];
    const float* Wih_b = (const float*)d_in[5];
    const float* Whh_b = (const float*)d_in[6];
    const float* b_b   = (const float*)d_in[7];
    const float* W_out = (const float*)d_in[8];
    const float* b_out = (const float*)d_in[9];
    const float* trans = (const float*)d_in[10];
    const float* startt= (const float*)d_in[11];
    const float* stopt = (const float*)d_in[12];

    char* ws = (char*)d_ws;
    float* X      = (float*)(ws);                           // 268,435,456 B  [2][32][32][512][64]
    float* h_hist = (float*)(ws + 268435456ull);            //  67,108,864 B  [16384][1024]
    f16*   ehi    = (f16*)  (ws + 335544320ull);            //  16,777,216 B
    f16*   elo    = (f16*)  (ws + 352321536ull);            //  16,777,216 B
    f16*   wihhi  = (f16*)  (ws + 369098752ull);            //   4,194,304 B
    f16*   wihlo  = (f16*)  (ws + 373293056ull);
    f16*   whhhi  = (f16*)  (ws + 377487360ull);
    f16*   whhlo  = (f16*)  (ws + 381681664ull);
    unsigned* hx  = (unsigned*)(ws + 385875968ull);         //     262,144 B  [2][2][32][512]
    float* feats  = (float*)(ws + 386138112ull);            //   1,048,576 B

    // init exchange buffers: tag field (bits 17:16) = 3
    hipMemsetAsync(hx, 0xFF, 262144, stream);

    k_split<<<1024, 256, 0, stream>>>(Wih_f, wihhi,          wihlo,          NG*EDIM);
    k_split<<<1024, 256, 0, stream>>>(Wih_b, wihhi + NG*EDIM, wihlo + NG*EDIM, NG*EDIM);
    k_split<<<1024, 256, 0, stream>>>(Whh_f, whhhi,          whhlo,          NG*EDIM);
    k_split<<<1024, 256, 0, stream>>>(Whh_b, whhhi + NG*EDIM, whhlo + NG*EDIM, NG*EDIM);
    k_gather<<<16384, 256, 0, stream>>>(sentence, embedding, ehi, elo);

    k_gemm<<<dim3(16, 128, 2), 512, 0, stream>>>(ehi, elo, wihhi, wihlo, b_f, b_b, X);

    hipFuncSetAttribute((const void*)k_rec, hipFuncAttributeMaxDynamicSharedMemorySize, 82944);
    k_rec<<<64, 512, 82944, stream>>>(X, whhhi, whhlo, hx, h_hist);

    k_feats<<<4096, 256, 0, stream>>>(h_hist, W_out, b_out, feats);
    k_viterbi<<<32, 64, 0, stream>>>(feats, trans, startt, stopt, (int*)d_out);
}

// Round 9
// 2364.382 us; speedup vs baseline: 1.7672x; 1.2210x over previous
//
#include <hip/hip_runtime.h>
#include <stdint.h>

#define BATCH 32
#define SEQ   512
#define EDIM  512
#define HID   512            // per-direction hidden
#define NG    2048           // 4*HID gate rows
#define NTAG  16

typedef _Float16 f16;
typedef _Float16 f16x4 __attribute__((ext_vector_type(4)));
typedef _Float16 f16x8 __attribute__((ext_vector_type(8)));
typedef float    f32x4 __attribute__((ext_vector_type(4)));

#define LO_SCALE 2048.0f
#define LO_INV   (1.0f/2048.0f)

// ---------------- prep: fp32 -> f16 hi/lo limb split (lo scaled by 2048) ---
__global__ __launch_bounds__(256) void k_split(const float* __restrict__ src,
                                               f16* __restrict__ hi, f16* __restrict__ lo, int n) {
    int i = blockIdx.x * blockDim.x + threadIdx.x;
    int stride = gridDim.x * blockDim.x;
    for (; i < n; i += stride) {
        float x = src[i];
        f16 h = (f16)x;
        hi[i] = h;
        lo[i] = (f16)((x - (float)h) * LO_SCALE);
    }
}

// ---------------- gather embedding rows + split -----------------------------
__global__ __launch_bounds__(256) void k_gather(const int* __restrict__ sent,
                                                const float* __restrict__ emb,
                                                f16* __restrict__ ehi, f16* __restrict__ elo) {
    int m = blockIdx.x;                  // 0..16383 = b*SEQ+s
    int idx = sent[m];
    const float* src = emb + (size_t)idx * EDIM;
    int k = threadIdx.x * 2;
    float2 v = *(const float2*)(src + k);
    f16 h0 = (f16)v.x, h1 = (f16)v.y;
    ehi[(size_t)m*EDIM + k]     = h0;
    ehi[(size_t)m*EDIM + k + 1] = h1;
    elo[(size_t)m*EDIM + k]     = (f16)((v.x - (float)h0) * LO_SCALE);
    elo[(size_t)m*EDIM + k + 1] = (f16)((v.y - (float)h1) * LO_SCALE);
}

__device__ __forceinline__ void gld16(const void* g, void* l) {
    __builtin_amdgcn_global_load_lds((const __attribute__((address_space(1))) uint32_t*)g,
                                     (__attribute__((address_space(3))) uint32_t*)l, 16, 0, 0);
}
__device__ __forceinline__ f32x4 mfma16(f16x8 a, f16x8 b, f32x4 c) {
    return __builtin_amdgcn_mfma_f32_16x16x32_f16(a, b, c, 0, 0, 0);
}

// ---------------- input projection: X = emb @ Wih^T + bias (f16x2 limbs) ----
// Output layout: X[dir][chunk 32][batch 32][seq 512][gate 4][unit 16] (f32)
__global__ __launch_bounds__(512, 2) void k_gemm(
    const f16* __restrict__ Ahi, const f16* __restrict__ Alo,    // [16384][512]
    const f16* __restrict__ Whi, const f16* __restrict__ Wlo,    // [2][2048][512]
    const float* __restrict__ bias_f, const float* __restrict__ bias_b,
    float* __restrict__ Xout)
{
    const int n0  = blockIdx.x * 128;
    const int m0  = blockIdx.y * 128;
    const int dir = blockIdx.z;
    const float* bias = dir ? bias_b : bias_f;
    const f16* Bhi = Whi + (size_t)dir * NG * EDIM;
    const f16* Blo = Wlo + (size_t)dir * NG * EDIM;
    float* X = Xout + (size_t)dir * 16384 * NG;

    __shared__ f16 sAh[128*64], sAl[128*64], sBh[128*64], sBl[128*64];  // 64 KiB

    const int tid  = threadIdx.x;
    const int lane = tid & 63;
    const int wave = tid >> 6;        // 0..7
    const int wr   = wave >> 2;       // 0..1  (64 rows)
    const int wc   = wave & 3;        // 0..3  (32 cols)

    f32x4 accH[4][2] = {};
    f32x4 accM[4][2] = {};

    for (int kt = 0; kt < 8; ++kt) {
        const int kbase = kt * 64;
        for (int sub = 0; sub < 2; ++sub) {
            int byte = sub*8192 + tid*16;
            int row  = byte >> 7;          // 0..127
            int up   = (byte >> 4) & 7;
            int u    = up ^ (row & 7);     // logical 16B unit
            const f16* ga  = Ahi + (size_t)(m0 + row)*EDIM + kbase + u*8;
            const f16* gal = Alo + (size_t)(m0 + row)*EDIM + kbase + u*8;
            const f16* gb  = Bhi + (size_t)(n0 + row)*EDIM + kbase + u*8;
            const f16* gbl = Blo + (size_t)(n0 + row)*EDIM + kbase + u*8;
            gld16(ga,  (char*)sAh + byte);
            gld16(gal, (char*)sAl + byte);
            gld16(gb,  (char*)sBh + byte);
            gld16(gbl, (char*)sBl + byte);
        }
        __syncthreads();
        for (int ks = 0; ks < 2; ++ks) {
            f16x8 fAh[4], fAl[4], fBh[2], fBl[2];
            #pragma unroll
            for (int mi = 0; mi < 4; ++mi) {
                int row = wr*64 + mi*16 + (lane & 15);
                int u   = ks*4 + (lane >> 4);
                int off = row*128 + (u ^ (row & 7))*16;
                fAh[mi] = *(const f16x8*)((const char*)sAh + off);
                fAl[mi] = *(const f16x8*)((const char*)sAl + off);
            }
            #pragma unroll
            for (int ni = 0; ni < 2; ++ni) {
                int row = wc*32 + ni*16 + (lane & 15);
                int u   = ks*4 + (lane >> 4);
                int off = row*128 + (u ^ (row & 7))*16;
                fBh[ni] = *(const f16x8*)((const char*)sBh + off);
                fBl[ni] = *(const f16x8*)((const char*)sBl + off);
            }
            #pragma unroll
            for (int mi = 0; mi < 4; ++mi)
                #pragma unroll
                for (int ni = 0; ni < 2; ++ni)
                    accH[mi][ni] = mfma16(fAh[mi], fBh[ni], accH[mi][ni]);
            #pragma unroll
            for (int mi = 0; mi < 4; ++mi)
                #pragma unroll
                for (int ni = 0; ni < 2; ++ni)
                    accM[mi][ni] = mfma16(fAh[mi], fBl[ni], accM[mi][ni]);
            #pragma unroll
            for (int mi = 0; mi < 4; ++mi)
                #pragma unroll
                for (int ni = 0; ni < 2; ++ni)
                    accM[mi][ni] = mfma16(fAl[mi], fBh[ni], accM[mi][ni]);
        }
        __syncthreads();
    }
    // epilogue: write relayout [chunk][b][s][gate][unit]
    #pragma unroll
    for (int ni = 0; ni < 2; ++ni) {
        int col = n0 + wc*32 + ni*16 + (lane & 15);
        float bv = bias[col];
        int gate  = col >> 9;
        int chunk = (col >> 4) & 31;
        int u     = col & 15;
        #pragma unroll
        for (int mi = 0; mi < 4; ++mi) {
            #pragma unroll
            for (int j = 0; j < 4; ++j) {
                int m = m0 + wr*64 + mi*16 + (lane >> 4)*4 + j;
                int b = m >> 9, s = m & 511;
                X[(((size_t)chunk*32 + b)*512 + s)*64 + gate*16 + u] =
                    accH[mi][ni][j] + accM[mi][ni][j]*LO_INV + bv;
            }
        }
    }
}

// ---------------- persistent bidirectional LSTM recurrence (v9) -------------
// 128 WGs: dir(2) x mt(2, batch half) x chunk(32, 16 units => 64 gate rows).
// Each WG: gates for 16 batch rows x 64 gate rows; per-WG work halved vs v8.
// Exchange all-to-all within (dir,mt) groups of 32 WGs; packed u32 with 2-bit
// step tag in bits 17:16; per-packet pend-mask busy poll (proven r5 scheme).
// Waves (g 4 x kh 2); Whh limbs in registers; LDS: 16-row h limb planes+gbuf.
__global__ __launch_bounds__(512, 1) void k_rec(
    const float* __restrict__ Xall,                               // [2][32][32][512][64]
    const f16* __restrict__ Whi, const f16* __restrict__ Wlo,     // [2][2048][512]
    unsigned* __restrict__ hx,                                    // [2][2][32][512] packed
    float* __restrict__ h_hist)                                   // [16384][1024]
{
    __shared__ char  hhiS[16384];             // h hi plane [16 rows][64 x 16B] swizzled
    __shared__ char  hloS[16384];             // h lo plane
    __shared__ float gbuf[2*4*16*17];         // [kh][g][row16][17]

    const int wg    = blockIdx.x;
    const int dir   = wg >> 6;
    const int mt    = (wg >> 5) & 1;
    const int chunk = wg & 31;
    const int u0    = chunk * 16;
    const int tid   = threadIdx.x;
    const int lane  = tid & 63;
    const int wave  = tid >> 6;
    const int g     = wave & 3;        // gate type
    const int kh    = wave >> 2;       // K half
    const int u     = lane & 15;
    const int q4    = lane >> 4;

    const float* X = Xall + (size_t)dir * 16384 * NG;
    unsigned* hxd = hx + (size_t)dir * 2 * BATCH * HID;

    const int pbl = tid >> 4;          // cell: local batch row 0..15 (tid<256)
    const int pu  = tid & 15;          // cell: unit within chunk
    const char* hrowH = hhiS + u*1024; // A row = local batch u
    const char* hrowL = hloS + u*1024;
    const int u7 = u & 7;

    // step-invariant Whh B-fragments -> registers (1 gate x 8 kt x hi/lo)
    f16x8 bhv[8], blv[8];
    {
        const size_t row = (size_t)(dir*NG + g*512 + u0 + u) * EDIM;
        const f16* ph = Whi + row + q4*8;
        const f16* pl = Wlo + row + q4*8;
        #pragma unroll
        for (int kt = 0; kt < 8; ++kt) {
            bhv[kt] = *(const f16x8*)(ph + (kh*8 + kt)*32);
            blv[kt] = *(const f16x8*)(pl + (kh*8 + kt)*32);
        }
    }

    float c = 0.0f;                   // cell state for (mt*16+pbl, u0+pu)

    for (int t = 0; t < SEQ; ++t) {
        const int s = dir ? (SEQ - 1 - t) : t;

        // X prefetch for the cell phase (contiguous 64B/row stream)
        float xv[4];
        {
            const float* xb = X + (((size_t)chunk*32 + (mt*16 + pbl))*512 + s)*64 + pu;
            #pragma unroll
            for (int gg = 0; gg < 4; ++gg) xv[gg] = xb[gg*16];
        }

        // fill h planes: 16 rows x 512 units = 2048 quads, 4 per thread
        if (t == 0) {
            #pragma unroll
            for (int i = 0; i < 4; ++i) {
                int q = i*512 + tid, row = q >> 7, kq = (q & 127)*4;
                int off = row*1024 + ((kq >> 3) ^ (row & 7))*16 + (kq & 4)*2;
                *(uint2*)(hhiS + off) = (uint2){0u, 0u};
                *(uint2*)(hloS + off) = (uint2){0u, 0u};
            }
        } else {
            const unsigned tag32 = ((unsigned)((t - 1) >> 1) & 3u) << 16;
            const unsigned* hsrc = hxd + (size_t)(t & 1)*BATCH*HID + (size_t)mt*16*HID;
            unsigned pend = 0xFu;
            while (pend) {
                unsigned long long va[4], vb[4];
                #pragma unroll
                for (int i = 0; i < 4; ++i) {
                    if (pend & (1u << i)) {
                        int q = i*512 + tid;
                        const unsigned long long* p =
                            (const unsigned long long*)(hsrc + (q >> 7)*HID + (q & 127)*4);
                        va[i] = __hip_atomic_load(p,     __ATOMIC_RELAXED, __HIP_MEMORY_SCOPE_AGENT);
                        vb[i] = __hip_atomic_load(p + 1, __ATOMIC_RELAXED, __HIP_MEMORY_SCOPE_AGENT);
                    }
                }
                #pragma unroll
                for (int i = 0; i < 4; ++i) {
                    if (!(pend & (1u << i))) continue;
                    unsigned w0 = (unsigned)va[i], w1 = (unsigned)(va[i] >> 32);
                    unsigned w2 = (unsigned)vb[i], w3 = (unsigned)(vb[i] >> 32);
                    if ((((w0 ^ tag32) | (w1 ^ tag32) | (w2 ^ tag32) | (w3 ^ tag32)) & 0x30000u) != 0u)
                        continue;   // not all words carry this step's tag yet
                    unsigned hi01 = (w0 & 0xffffu) | (w1 << 16);
                    unsigned hi23 = (w2 & 0xffffu) | (w3 << 16);
                    unsigned lo01 = (w0 >> 16) | (w1 & 0xffff0000u);
                    unsigned lo23 = (w2 >> 16) | (w3 & 0xffff0000u);
                    int q = i*512 + tid, row = q >> 7, kq = (q & 127)*4;
                    int off = row*1024 + ((kq >> 3) ^ (row & 7))*16 + (kq & 4)*2;
                    *(uint2*)(hhiS + off) = (uint2){hi01, hi23};
                    *(uint2*)(hloS + off) = (uint2){lo01, lo23};
                    pend &= ~(1u << i);
                }
            }
        }
        __syncthreads();                       // (1) fill done

        // MFMA: partial gates for this wave's (g, kh): M=16 batch, N=16 units
        f32x4 aH = {0.f,0.f,0.f,0.f}, aM1 = aH, aM2 = aH;
        #pragma unroll
        for (int kt = 0; kt < 8; ++kt) {
            int ug = (kh*8 + kt)*4 + q4;
            f16x8 ah = *(const f16x8*)(hrowH + (ug ^ u7)*16);
            f16x8 al = *(const f16x8*)(hrowL + (ug ^ u7)*16);
            aH  = mfma16(ah, bhv[kt], aH);
            aM1 = mfma16(ah, blv[kt], aM1);
            aM2 = mfma16(al, bhv[kt], aM2);
        }
        #pragma unroll
        for (int j = 0; j < 4; ++j) {
            int row = q4*4 + j;                // local batch row
            gbuf[(kh*4 + g)*272 + row*17 + u] = aH[j] + (aM1[j] + aM2[j]) * LO_INV;
        }
        __syncthreads();                       // (2) gbuf ready; plane reads done

        // pointwise LSTM cell + packed tagged store (tid<256: 16 rows x 16 units)
        if (tid < 256) {
            float gs[4];
            #pragma unroll
            for (int gg = 0; gg < 4; ++gg)
                gs[gg] = gbuf[(0*4 + gg)*272 + pbl*17 + pu]
                       + gbuf[(1*4 + gg)*272 + pbl*17 + pu] + xv[gg];
            float si = 1.0f / (1.0f + __expf(-gs[0]));
            float sf = 1.0f / (1.0f + __expf(-gs[1]));
            float tg = 1.0f - 2.0f / (__expf(2.0f*gs[2]) + 1.0f);
            float so = 1.0f / (1.0f + __expf(-gs[3]));
            c = sf * c + si * tg;
            float hval = so * (1.0f - 2.0f / (__expf(2.0f*c) + 1.0f));
            f16 hh = (f16)hval;
            f16 hl = (f16)((hval - (float)hh) * LO_SCALE);
            unsigned packed = (unsigned)__builtin_bit_cast(unsigned short, hh)
                            | ((unsigned)__builtin_bit_cast(unsigned short, hl) << 16);
            packed = (packed & ~0x30000u) | ((((unsigned)t >> 1) & 3u) << 16);
            int b = mt*16 + pbl;
            unsigned* hdst = hxd + (size_t)((t + 1) & 1)*BATCH*HID + b*HID + u0 + pu;
            __hip_atomic_store(hdst, packed, __ATOMIC_RELAXED, __HIP_MEMORY_SCOPE_AGENT);
            // h_hist off the critical path; non-temporal (keep L2 clean)
            __builtin_nontemporal_store(hval,
                h_hist + ((size_t)b*SEQ + s)*1024 + dir*HID + u0 + pu);
        }
    }
}

// ---------------- output projection: feats = H @ W_out^T + b_out ------------
__global__ __launch_bounds__(256) void k_feats(
    const float* __restrict__ H,      // [16384][1024]
    const float* __restrict__ Wout,   // [16][1024]
    const float* __restrict__ bout,   // [16]
    float* __restrict__ feats)        // [16384][16]
{
    __shared__ float Wt[1024][16];    // 64 KiB, transposed
    int tid = threadIdx.x;
    for (int i = tid; i < 16384; i += 256)
        Wt[i >> 4][i & 15] = Wout[(i & 15)*1024 + (i >> 4)];
    __syncthreads();
    int wave = tid >> 6, lane = tid & 63;
    int row = blockIdx.x * 4 + wave;
    const float* hrow = H + (size_t)row * 1024;
    float acc[16];
    #pragma unroll
    for (int t = 0; t < 16; ++t) acc[t] = 0.f;
    #pragma unroll
    for (int cc = 0; cc < 4; ++cc) {
        float4 hv = *(const float4*)(hrow + cc*256 + lane*4);
        #pragma unroll
        for (int j = 0; j < 4; ++j) {
            int k = cc*256 + lane*4 + j;
            float h = (&hv.x)[j];
            #pragma unroll
            for (int tg = 0; tg < 16; ++tg) acc[tg] += h * Wt[k][tg];
        }
    }
    #pragma unroll
    for (int off = 32; off >= 1; off >>= 1) {
        #pragma unroll
        for (int tg = 0; tg < 16; ++tg) acc[tg] += __shfl_xor(acc[tg], off);
    }
    if (lane == 0) {
        #pragma unroll
        for (int tg = 0; tg < 16; ++tg)
            feats[(size_t)row*16 + tg] = acc[tg] + bout[tg];
    }
}

// ---------------- Viterbi + backtrace (one wave per batch) ------------------
__global__ __launch_bounds__(64) void k_viterbi(
    const float* __restrict__ feats,   // [32][512][16]
    const float* __restrict__ trans,   // [16][16] trans[prev][cur]
    const float* __restrict__ startt, const float* __restrict__ stopt,
    int* __restrict__ out)             // [32][512]
{
    __shared__ unsigned char bp[511*16];
    int b = blockIdx.x;
    int lane = threadIdx.x;
    int cur = lane & 15;
    int q   = lane >> 4;
    float tr[4];
    #pragma unroll
    for (int i = 0; i < 4; ++i) tr[i] = trans[(q*4 + i)*16 + cur];
    const float* fb = feats + (size_t)b * SEQ * NTAG;
    float v = fb[cur] + startt[cur];
    for (int s = 1; s < SEQ; ++s) {
        float best = -1e30f; int bi = 0;
        #pragma unroll
        for (int i = 0; i < 4; ++i) {
            float pv = __shfl(v, q*4 + i);
            float sc = pv + tr[i];
            if (sc > best) { best = sc; bi = q*4 + i; }   // first-max within quarter
        }
        #pragma unroll
        for (int off = 16; off <= 32; off <<= 1) {
            float ob = __shfl_xor(best, off);
            int   oi = __shfl_xor(bi, off);
            if (ob > best || (ob == best && oi < bi)) { best = ob; bi = oi; }
        }
        if (lane < 16) bp[(s - 1)*16 + cur] = (unsigned char)bi;
        v = best + fb[s*16 + cur];
    }
    float sc = v + stopt[cur];
    int bc = cur;
    #pragma unroll
    for (int off = 1; off <= 32; off <<= 1) {
        float os = __shfl_xor(sc, off);
        int   oc = __shfl_xor(bc, off);
        if (os > sc || (os == sc && oc < bc)) { sc = os; bc = oc; }
    }
    __syncthreads();
    if (lane == 0) {
        int curt = bc;
        out[b*SEQ + SEQ - 1] = curt;
        for (int s2 = SEQ - 2; s2 >= 0; --s2) {
            curt = bp[s2*16 + curt];
            out[b*SEQ + s2] = curt;
        }
    }
}

// ---------------- launch ----------------------------------------------------
extern "C" void kernel_launch(void* const* d_in, const int* in_sizes, int n_in,
                              void* d_out, int out_size, void* d_ws, size_t ws_size,
                              hipStream_t stream) {
    (void)in_sizes; (void)n_in; (void)out_size; (void)ws_size;
    const int*   sentence  = (const int*)  d_in[0];
    const float* embedding = (const float*)d_in[1];
    const float* Wih_f = (const float*)d_in[2];
    const float* Whh_f = (const float*)d_in[3];
    const float* b_f   = (const float*)d_in[4];
    const float* Wih_b = (const float*)d_in[5];
    const float* Whh_b = (const float*)d_in[6];
    const float* b_b   = (const float*)d_in[7];
    const float* W_out = (const float*)d_in[8];
    const float* b_out = (const float*)d_in[9];
    const float* trans = (const float*)d_in[10];
    const float* startt= (const float*)d_in[11];
    const float* stopt = (const float*)d_in[12];

    char* ws = (char*)d_ws;
    float* X      = (float*)(ws);                           // 268,435,456 B  [2][32][32][512][64]
    float* h_hist = (float*)(ws + 268435456ull);            //  67,108,864 B  [16384][1024]
    f16*   ehi    = (f16*)  (ws + 335544320ull);            //  16,777,216 B
    f16*   elo    = (f16*)  (ws + 352321536ull);            //  16,777,216 B
    f16*   wihhi  = (f16*)  (ws + 369098752ull);            //   4,194,304 B
    f16*   wihlo  = (f16*)  (ws + 373293056ull);
    f16*   whhhi  = (f16*)  (ws + 377487360ull);
    f16*   whhlo  = (f16*)  (ws + 381681664ull);
    unsigned* hx  = (unsigned*)(ws + 385875968ull);         //     262,144 B  [2][2][32][512]
    float* feats  = (float*)(ws + 386138112ull);            //   1,048,576 B

    // init exchange buffers: tag field (bits 17:16) = 3
    hipMemsetAsync(hx, 0xFF, 262144, stream);

    k_split<<<1024, 256, 0, stream>>>(Wih_f, wihhi,          wihlo,          NG*EDIM);
    k_split<<<1024, 256, 0, stream>>>(Wih_b, wihhi + NG*EDIM, wihlo + NG*EDIM, NG*EDIM);
    k_split<<<1024, 256, 0, stream>>>(Whh_f, whhhi,          whhlo,          NG*EDIM);
    k_split<<<1024, 256, 0, stream>>>(Whh_b, whhhi + NG*EDIM, whhlo + NG*EDIM, NG*EDIM);
    k_gather<<<16384, 256, 0, stream>>>(sentence, embedding, ehi, elo);

    k_gemm<<<dim3(16, 128, 2), 512, 0, stream>>>(ehi, elo, wihhi, wihlo, b_f, b_b, X);

    k_rec<<<128, 512, 0, stream>>>(X, whhhi, whhlo, hx, h_hist);

    k_feats<<<4096, 256, 0, stream>>>(h_hist, W_out, b_out, feats);
    k_viterbi<<<32, 64, 0, stream>>>(feats, trans, startt, stopt, (int*)d_out);
}

// Round 10
// 2290.586 us; speedup vs baseline: 1.8241x; 1.0322x over previous
//
#include <hip/hip_runtime.h>
#include <stdint.h>

#define BATCH 32
#define SEQ   512
#define EDIM  512
#define HID   512            // per-direction hidden
#define NG    2048           // 4*HID gate rows
#define NTAG  16

typedef _Float16 f16;
typedef _Float16 f16x4 __attribute__((ext_vector_type(4)));
typedef _Float16 f16x8 __attribute__((ext_vector_type(8)));
typedef float    f32x4 __attribute__((ext_vector_type(4)));

#define LO_SCALE 2048.0f
#define LO_INV   (1.0f/2048.0f)

// ---------------- prep: fp32 -> f16 hi/lo limb split (lo scaled by 2048) ---
__global__ __launch_bounds__(256) void k_split(const float* __restrict__ src,
                                               f16* __restrict__ hi, f16* __restrict__ lo, int n) {
    int i = blockIdx.x * blockDim.x + threadIdx.x;
    int stride = gridDim.x * blockDim.x;
    for (; i < n; i += stride) {
        float x = src[i];
        f16 h = (f16)x;
        hi[i] = h;
        lo[i] = (f16)((x - (float)h) * LO_SCALE);
    }
}

// ---------------- gather embedding rows + split -----------------------------
__global__ __launch_bounds__(256) void k_gather(const int* __restrict__ sent,
                                                const float* __restrict__ emb,
                                                f16* __restrict__ ehi, f16* __restrict__ elo) {
    int m = blockIdx.x;                  // 0..16383 = b*SEQ+s
    int idx = sent[m];
    const float* src = emb + (size_t)idx * EDIM;
    int k = threadIdx.x * 2;
    float2 v = *(const float2*)(src + k);
    f16 h0 = (f16)v.x, h1 = (f16)v.y;
    ehi[(size_t)m*EDIM + k]     = h0;
    ehi[(size_t)m*EDIM + k + 1] = h1;
    elo[(size_t)m*EDIM + k]     = (f16)((v.x - (float)h0) * LO_SCALE);
    elo[(size_t)m*EDIM + k + 1] = (f16)((v.y - (float)h1) * LO_SCALE);
}

__device__ __forceinline__ void gld16(const void* g, void* l) {
    __builtin_amdgcn_global_load_lds((const __attribute__((address_space(1))) uint32_t*)g,
                                     (__attribute__((address_space(3))) uint32_t*)l, 16, 0, 0);
}
__device__ __forceinline__ f32x4 mfma16(f16x8 a, f16x8 b, f32x4 c) {
    return __builtin_amdgcn_mfma_f32_16x16x32_f16(a, b, c, 0, 0, 0);
}

// ---------------- persistent fused BiLSTM (v10 = v9 + fused input proj) -----
// 128 WGs: dir(2) x mt(2) x chunk(32, 16 units => 64 gate rows).
// Per step: gates = emb@Wih + h@Whh + bias, all in one MFMA phase.
//  - Wih/Whh limb B-fragments: step-invariant, in registers (~128 VGPR).
//  - emb A-tile (pre-limb-split by k_gather): 4x global_load_lds with
//    pre-swizzled source, issued BEFORE the h-poll (latency hides under it).
//  - h exchange: packed u32 (f16 hi | lo<<16), 2-bit step tag in bits 17:16,
//    per-packet pend-mask busy poll (r5/r9 proven scheme).
__global__ __launch_bounds__(512, 1) void k_rec(
    const f16* __restrict__ ehi,  const f16* __restrict__ elo,   // [16384][512]
    const f16* __restrict__ Whhi, const f16* __restrict__ Whlo,  // [2][2048][512]
    const f16* __restrict__ Wihi, const f16* __restrict__ Wilo,  // [2][2048][512]
    const float* __restrict__ b_f, const float* __restrict__ b_b,
    unsigned* __restrict__ hx,                                   // [2][2][32][512] packed
    float* __restrict__ h_hist)                                  // [16384][1024]
{
    __shared__ char  hhiS[16384];             // h   hi plane [16 rows][64 x 16B] swizzled
    __shared__ char  hloS[16384];             // h   lo plane
    __shared__ char  ehiS[16384];             // emb hi plane (same layout)
    __shared__ char  eloS[16384];             // emb lo plane
    __shared__ float gbuf[2*4*16*17];         // [kh][g][row16][17]

    const int wg    = blockIdx.x;
    const int dir   = wg >> 6;
    const int mt    = (wg >> 5) & 1;
    const int chunk = wg & 31;
    const int u0    = chunk * 16;
    const int tid   = threadIdx.x;
    const int lane  = tid & 63;
    const int wave  = tid >> 6;
    const int g     = wave & 3;        // gate type
    const int kh    = wave >> 2;       // K half
    const int u     = lane & 15;
    const int q4    = lane >> 4;

    unsigned* hxd = hx + (size_t)dir * 2 * BATCH * HID;

    const int pbl = tid >> 4;          // cell: local batch row 0..15 (tid<256)
    const int pu  = tid & 15;          // cell: unit within chunk
    const char* hrowH = hhiS + u*1024; // A row = local batch row u
    const char* hrowL = hloS + u*1024;
    const char* erowH = ehiS + u*1024;
    const char* erowL = eloS + u*1024;
    const int u7 = u & 7;

    // step-invariant Whh + Wih B-fragments -> registers (8 kt x hi/lo each)
    f16x8 bhv[8], blv[8], wbh[8], wbl[8];
    {
        const size_t row = (size_t)(dir*NG + g*512 + u0 + u) * EDIM;
        const f16* ph = Whhi + row + q4*8;
        const f16* pl = Whlo + row + q4*8;
        const f16* qh = Wihi + row + q4*8;
        const f16* ql = Wilo + row + q4*8;
        #pragma unroll
        for (int kt = 0; kt < 8; ++kt) {
            bhv[kt] = *(const f16x8*)(ph + (kh*8 + kt)*32);
            blv[kt] = *(const f16x8*)(pl + (kh*8 + kt)*32);
            wbh[kt] = *(const f16x8*)(qh + (kh*8 + kt)*32);
            wbl[kt] = *(const f16x8*)(ql + (kh*8 + kt)*32);
        }
    }

    // per-cell bias (4 gates), loaded once
    float bv[4];
    {
        const float* bias = dir ? b_b : b_f;
        #pragma unroll
        for (int gg = 0; gg < 4; ++gg) bv[gg] = bias[gg*512 + u0 + pu];
    }

    // emb staging geometry: wave w fills plane row (o*8 + w), lane l fetches
    // logical unit (l ^ w) so the LDS write is linear (gld_lds constraint).
    const int grow0 = mt*16 + wave;            // o=0 source row (local +8 for o=1)
    const int srcu  = (lane ^ wave) * 8;       // f16 offset within source row

    float c = 0.0f;                   // cell state for (mt*16+pbl, u0+pu)

    for (int t = 0; t < SEQ; ++t) {
        const int s = dir ? (SEQ - 1 - t) : t;

        // ---- issue emb plane loads for step t (latency hides under poll) ----
        {
            size_t r0 = ((size_t)(grow0)*SEQ + s) * EDIM + srcu;
            size_t r1 = ((size_t)(grow0 + 8)*SEQ + s) * EDIM + srcu;
            gld16(ehi + r0, ehiS + tid*16);
            gld16(ehi + r1, ehiS + 8192 + tid*16);
            gld16(elo + r0, eloS + tid*16);
            gld16(elo + r1, eloS + 8192 + tid*16);
        }

        // ---- fill h planes: poll packed exchange data for this step's tag ----
        if (t == 0) {
            #pragma unroll
            for (int i = 0; i < 4; ++i) {
                int q = i*512 + tid, row = q >> 7, kq = (q & 127)*4;
                int off = row*1024 + ((kq >> 3) ^ (row & 7))*16 + (kq & 4)*2;
                *(uint2*)(hhiS + off) = (uint2){0u, 0u};
                *(uint2*)(hloS + off) = (uint2){0u, 0u};
            }
        } else {
            const unsigned tag32 = ((unsigned)((t - 1) >> 1) & 3u) << 16;
            const unsigned* hsrc = hxd + (size_t)(t & 1)*BATCH*HID + (size_t)mt*16*HID;
            unsigned pend = 0xFu;
            while (pend) {
                unsigned long long va[4], vb[4];
                #pragma unroll
                for (int i = 0; i < 4; ++i) {
                    if (pend & (1u << i)) {
                        int q = i*512 + tid;
                        const unsigned long long* p =
                            (const unsigned long long*)(hsrc + (q >> 7)*HID + (q & 127)*4);
                        va[i] = __hip_atomic_load(p,     __ATOMIC_RELAXED, __HIP_MEMORY_SCOPE_AGENT);
                        vb[i] = __hip_atomic_load(p + 1, __ATOMIC_RELAXED, __HIP_MEMORY_SCOPE_AGENT);
                    }
                }
                #pragma unroll
                for (int i = 0; i < 4; ++i) {
                    if (!(pend & (1u << i))) continue;
                    unsigned w0 = (unsigned)va[i], w1 = (unsigned)(va[i] >> 32);
                    unsigned w2 = (unsigned)vb[i], w3 = (unsigned)(vb[i] >> 32);
                    if ((((w0 ^ tag32) | (w1 ^ tag32) | (w2 ^ tag32) | (w3 ^ tag32)) & 0x30000u) != 0u)
                        continue;   // not all words carry this step's tag yet
                    unsigned hi01 = (w0 & 0xffffu) | (w1 << 16);
                    unsigned hi23 = (w2 & 0xffffu) | (w3 << 16);
                    unsigned lo01 = (w0 >> 16) | (w1 & 0xffff0000u);
                    unsigned lo23 = (w2 >> 16) | (w3 & 0xffff0000u);
                    int q = i*512 + tid, row = q >> 7, kq = (q & 127)*4;
                    int off = row*1024 + ((kq >> 3) ^ (row & 7))*16 + (kq & 4)*2;
                    *(uint2*)(hhiS + off) = (uint2){hi01, hi23};
                    *(uint2*)(hloS + off) = (uint2){lo01, lo23};
                    pend &= ~(1u << i);
                }
            }
        }
        __syncthreads();                 // h planes + emb planes (vmcnt 0) ready

        // ---- MFMA: gates = emb@Wih + h@Whh for this wave's (g, kh) ----
        f32x4 aH = {0.f,0.f,0.f,0.f}, aM1 = aH, aM2 = aH;
        #pragma unroll
        for (int kt = 0; kt < 8; ++kt) {
            int off = (((kh*8 + kt)*4 + q4) ^ u7) * 16;
            f16x8 eh = *(const f16x8*)(erowH + off);
            f16x8 el = *(const f16x8*)(erowL + off);
            f16x8 ah = *(const f16x8*)(hrowH + off);
            f16x8 al = *(const f16x8*)(hrowL + off);
            aH  = mfma16(eh, wbh[kt], aH);
            aM1 = mfma16(eh, wbl[kt], aM1);
            aM2 = mfma16(el, wbh[kt], aM2);
            aH  = mfma16(ah, bhv[kt], aH);
            aM1 = mfma16(ah, blv[kt], aM1);
            aM2 = mfma16(al, bhv[kt], aM2);
        }
        #pragma unroll
        for (int j = 0; j < 4; ++j) {
            int row = q4*4 + j;                // local batch row
            gbuf[(kh*4 + g)*272 + row*17 + u] = aH[j] + (aM1[j] + aM2[j]) * LO_INV;
        }
        __syncthreads();                       // gbuf ready; plane reads done

        // ---- pointwise LSTM cell + packed tagged store ----
        if (tid < 256) {
            float gs[4];
            #pragma unroll
            for (int gg = 0; gg < 4; ++gg)
                gs[gg] = gbuf[(0*4 + gg)*272 + pbl*17 + pu]
                       + gbuf[(1*4 + gg)*272 + pbl*17 + pu] + bv[gg];
            float si = 1.0f / (1.0f + __expf(-gs[0]));
            float sf = 1.0f / (1.0f + __expf(-gs[1]));
            float tg = 1.0f - 2.0f / (__expf(2.0f*gs[2]) + 1.0f);
            float so = 1.0f / (1.0f + __expf(-gs[3]));
            c = sf * c + si * tg;
            float hval = so * (1.0f - 2.0f / (__expf(2.0f*c) + 1.0f));
            f16 hh = (f16)hval;
            f16 hl = (f16)((hval - (float)hh) * LO_SCALE);
            unsigned packed = (unsigned)__builtin_bit_cast(unsigned short, hh)
                            | ((unsigned)__builtin_bit_cast(unsigned short, hl) << 16);
            packed = (packed & ~0x30000u) | ((((unsigned)t >> 1) & 3u) << 16);
            int b = mt*16 + pbl;
            unsigned* hdst = hxd + (size_t)((t + 1) & 1)*BATCH*HID + b*HID + u0 + pu;
            __hip_atomic_store(hdst, packed, __ATOMIC_RELAXED, __HIP_MEMORY_SCOPE_AGENT);
            // h_hist off the critical path; non-temporal (keep L2 clean)
            __builtin_nontemporal_store(hval,
                h_hist + ((size_t)b*SEQ + s)*1024 + dir*HID + u0 + pu);
        }
    }
}

// ---------------- output projection: feats = H @ W_out^T + b_out ------------
__global__ __launch_bounds__(256) void k_feats(
    const float* __restrict__ H,      // [16384][1024]
    const float* __restrict__ Wout,   // [16][1024]
    const float* __restrict__ bout,   // [16]
    float* __restrict__ feats)        // [16384][16]
{
    __shared__ float Wt[1024][16];    // 64 KiB, transposed
    int tid = threadIdx.x;
    for (int i = tid; i < 16384; i += 256)
        Wt[i >> 4][i & 15] = Wout[(i & 15)*1024 + (i >> 4)];
    __syncthreads();
    int wave = tid >> 6, lane = tid & 63;
    int row = blockIdx.x * 4 + wave;
    const float* hrow = H + (size_t)row * 1024;
    float acc[16];
    #pragma unroll
    for (int t = 0; t < 16; ++t) acc[t] = 0.f;
    #pragma unroll
    for (int cc = 0; cc < 4; ++cc) {
        float4 hv = *(const float4*)(hrow + cc*256 + lane*4);
        #pragma unroll
        for (int j = 0; j < 4; ++j) {
            int k = cc*256 + lane*4 + j;
            float h = (&hv.x)[j];
            #pragma unroll
            for (int tg = 0; tg < 16; ++tg) acc[tg] += h * Wt[k][tg];
        }
    }
    #pragma unroll
    for (int off = 32; off >= 1; off >>= 1) {
        #pragma unroll
        for (int tg = 0; tg < 16; ++tg) acc[tg] += __shfl_xor(acc[tg], off);
    }
    if (lane == 0) {
        #pragma unroll
        for (int tg = 0; tg < 16; ++tg)
            feats[(size_t)row*16 + tg] = acc[tg] + bout[tg];
    }
}

// ---------------- Viterbi + backtrace (one wave per batch) ------------------
__global__ __launch_bounds__(64) void k_viterbi(
    const float* __restrict__ feats,   // [32][512][16]
    const float* __restrict__ trans,   // [16][16] trans[prev][cur]
    const float* __restrict__ startt, const float* __restrict__ stopt,
    int* __restrict__ out)             // [32][512]
{
    __shared__ unsigned char bp[511*16];
    int b = blockIdx.x;
    int lane = threadIdx.x;
    int cur = lane & 15;
    int q   = lane >> 4;
    float tr[4];
    #pragma unroll
    for (int i = 0; i < 4; ++i) tr[i] = trans[(q*4 + i)*16 + cur];
    const float* fb = feats + (size_t)b * SEQ * NTAG;
    float v = fb[cur] + startt[cur];
    for (int s = 1; s < SEQ; ++s) {
        float best = -1e30f; int bi = 0;
        #pragma unroll
        for (int i = 0; i < 4; ++i) {
            float pv = __shfl(v, q*4 + i);
            float sc = pv + tr[i];
            if (sc > best) { best = sc; bi = q*4 + i; }   // first-max within quarter
        }
        #pragma unroll
        for (int off = 16; off <= 32; off <<= 1) {
            float ob = __shfl_xor(best, off);
            int   oi = __shfl_xor(bi, off);
            if (ob > best || (ob == best && oi < bi)) { best = ob; bi = oi; }
        }
        if (lane < 16) bp[(s - 1)*16 + cur] = (unsigned char)bi;
        v = best + fb[s*16 + cur];
    }
    float sc = v + stopt[cur];
    int bc = cur;
    #pragma unroll
    for (int off = 1; off <= 32; off <<= 1) {
        float os = __shfl_xor(sc, off);
        int   oc = __shfl_xor(bc, off);
        if (os > sc || (os == sc && oc < bc)) { sc = os; bc = oc; }
    }
    __syncthreads();
    if (lane == 0) {
        int curt = bc;
        out[b*SEQ + SEQ - 1] = curt;
        for (int s2 = SEQ - 2; s2 >= 0; --s2) {
            curt = bp[s2*16 + curt];
            out[b*SEQ + s2] = curt;
        }
    }
}

// ---------------- launch ----------------------------------------------------
extern "C" void kernel_launch(void* const* d_in, const int* in_sizes, int n_in,
                              void* d_out, int out_size, void* d_ws, size_t ws_size,
                              hipStream_t stream) {
    (void)in_sizes; (void)n_in; (void)out_size; (void)ws_size;
    const int*   sentence  = (const int*)  d_in[0];
    const float* embedding = (const float*)d_in[1];
    const float* Wih_f = (const float*)d_in[2];
    const float* Whh_f = (const float*)d_in[3];
    const float* b_f   = (const float*)d_in[4];
    const float* Wih_b = (const float*)d_in[5];
    const float* Whh_b = (const float*)d_in[6];
    const float* b_b   = (const float*)d_in[7];
    const float* W_out = (const float*)d_in[8];
    const float* b_out = (const float*)d_in[9];
    const float* trans = (const float*)d_in[10];
    const float* startt= (const float*)d_in[11];
    const float* stopt = (const float*)d_in[12];

    char* ws = (char*)d_ws;
    float* h_hist = (float*)(ws);                           //  67,108,864 B  [16384][1024]
    f16*   ehi    = (f16*)  (ws +  67108864ull);            //  16,777,216 B
    f16*   elo    = (f16*)  (ws +  83886080ull);            //  16,777,216 B
    f16*   wihhi  = (f16*)  (ws + 100663296ull);            //   4,194,304 B
    f16*   wihlo  = (f16*)  (ws + 104857600ull);
    f16*   whhhi  = (f16*)  (ws + 109051904ull);
    f16*   whhlo  = (f16*)  (ws + 113246208ull);
    unsigned* hx  = (unsigned*)(ws + 117440512ull);         //     262,144 B  [2][2][32][512]
    float* feats  = (float*)(ws + 117702656ull);            //   1,048,576 B

    // init exchange buffers: tag field (bits 17:16) = 3
    hipMemsetAsync(hx, 0xFF, 262144, stream);

    k_split<<<1024, 256, 0, stream>>>(Wih_f, wihhi,          wihlo,          NG*EDIM);
    k_split<<<1024, 256, 0, stream>>>(Wih_b, wihhi + NG*EDIM, wihlo + NG*EDIM, NG*EDIM);
    k_split<<<1024, 256, 0, stream>>>(Whh_f, whhhi,          whhlo,          NG*EDIM);
    k_split<<<1024, 256, 0, stream>>>(Whh_b, whhhi + NG*EDIM, whhlo + NG*EDIM, NG*EDIM);
    k_gather<<<16384, 256, 0, stream>>>(sentence, embedding, ehi, elo);

    k_rec<<<128, 512, 0, stream>>>(ehi, elo, whhhi, whhlo, wihhi, wihlo,
                                   b_f, b_b, hx, h_hist);

    k_feats<<<4096, 256, 0, stream>>>(h_hist, W_out, b_out, feats);
    k_viterbi<<<32, 64, 0, stream>>>(feats, trans, startt, stopt, (int*)d_out);
}